// Round 3
// baseline (3098.293 us; speedup 1.0000x reference)
//
#include <hip/hip_runtime.h>

namespace {

constexpr int Bb = 8;
constexpr int Nn = 4097;
constexpr int Cc = 768;
constexpr int Hh = 12;
constexpr int HD = 64;
constexpr int Aa = 49;
constexpr int LDQ = 3 * Cc;        // 2304 (qkv row stride)
constexpr int NCH = 8;             // j-chunks for agent attention
constexpr int CHUNK = (Nn + NCH - 1) / NCH;  // 513
constexpr float SCALE = 0.125f;    // hd^-0.5

// ---------------------------------------------------------------------------
// Generic fp32 GEMM: C[M x N] = A[M x K] @ B[K x N] (+ bias), 128x128 tile,
// 256 threads, 8x8 per thread, BK=16. N and K must be multiples of 128/16.
// ---------------------------------------------------------------------------
__global__ __launch_bounds__(256) void gemm128(
    const float* __restrict__ Am, const float* __restrict__ Bm,
    float* __restrict__ Cm, const float* __restrict__ bias,
    int Mr, int lda, int ldb, int ldc, int Kc) {
  __shared__ float As[16][132];   // transposed A tile [k][m], +4 pad
  __shared__ float Bs[16][132];   // B tile [k][n], +4 pad (16B-aligned rows)
  const int t = threadIdx.x;
  const int tx = t & 15, ty = t >> 4;
  const int m0 = blockIdx.y * 128, n0 = blockIdx.x * 128;
  float acc[8][8];
#pragma unroll
  for (int i = 0; i < 8; ++i)
#pragma unroll
    for (int j = 0; j < 8; ++j) acc[i][j] = 0.f;

  for (int k0 = 0; k0 < Kc; k0 += 16) {
    __syncthreads();
#pragma unroll
    for (int l = 0; l < 2; ++l) {           // A: 128 rows x 16 k, 512 float4
      int idx = t + l * 256;
      int row = idx >> 2;
      int k4 = (idx & 3) << 2;
      float4 a = make_float4(0.f, 0.f, 0.f, 0.f);
      int grow = m0 + row;
      if (grow < Mr) a = *(const float4*)&Am[(size_t)grow * lda + k0 + k4];
      As[k4 + 0][row] = a.x; As[k4 + 1][row] = a.y;
      As[k4 + 2][row] = a.z; As[k4 + 3][row] = a.w;
    }
#pragma unroll
    for (int l = 0; l < 2; ++l) {           // B: 16 k x 128 n
      int idx = t + l * 256;
      int kr = idx >> 5;
      int nn = (idx & 31) << 2;
      *(float4*)&Bs[kr][nn] =
          *(const float4*)&Bm[(size_t)(k0 + kr) * ldb + n0 + nn];
    }
    __syncthreads();
#pragma unroll
    for (int kk = 0; kk < 16; ++kk) {
      float a[8], b[8];
      *(float4*)&a[0] = *(const float4*)&As[kk][8 * ty];
      *(float4*)&a[4] = *(const float4*)&As[kk][8 * ty + 4];
      *(float4*)&b[0] = *(const float4*)&Bs[kk][8 * tx];
      *(float4*)&b[4] = *(const float4*)&Bs[kk][8 * tx + 4];
#pragma unroll
      for (int i = 0; i < 8; ++i)
#pragma unroll
        for (int j = 0; j < 8; ++j) acc[i][j] += a[i] * b[j];
    }
  }

#pragma unroll
  for (int ii = 0; ii < 8; ++ii) {
    int grow = m0 + 8 * ty + ii;
    if (grow < Mr) {
#pragma unroll
      for (int j4 = 0; j4 < 2; ++j4) {
        int gcol = n0 + 8 * tx + j4 * 4;
        float4 o;
        o.x = acc[ii][j4 * 4 + 0]; o.y = acc[ii][j4 * 4 + 1];
        o.z = acc[ii][j4 * 4 + 2]; o.w = acc[ii][j4 * 4 + 3];
        if (bias) {
          o.x += bias[gcol + 0]; o.y += bias[gcol + 1];
          o.z += bias[gcol + 2]; o.w += bias[gcol + 3];
        }
        *(float4*)&Cm[(size_t)grow * ldc + gcol] = o;
      }
    }
  }
}

// ---------------------------------------------------------------------------
// Adaptive-pool agents: at[bg,a,c] = mean over q rows [s,e) of q[bg,l,c].
// ---------------------------------------------------------------------------
__global__ __launch_bounds__(256) void pool_agents(
    const float* __restrict__ qkv, float* __restrict__ at) {
  const int ba = blockIdx.x;
  const int bg = ba / Aa, a = ba % Aa;
  const int s = (a * 4096) / 49;
  const int e = ((a + 1) * 4096 + 48) / 49;
  const float w = 1.0f / (float)(e - s);
  const int t = threadIdx.x;
  for (int c = t; c < Cc; c += 256) {
    float sum = 0.f;
    for (int l = s; l < e; ++l)
      sum += qkv[(size_t)(bg * Nn + l) * LDQ + c];
    at[(size_t)(bg * Aa + a) * Cc + c] = sum * w;
  }
}

// ---------------------------------------------------------------------------
// Agent attention (no max-subtraction: scores tiny), partial over a j-chunk:
// paccv[bgh,ch,a,c] = sum_j exp(s)*v,  paccs[bgh,ch,a] = sum_j exp(s).
// K tile slot-XOR swizzled (T2); V tile row-major [jj][c] (+4 pad).
// ---------------------------------------------------------------------------
__global__ __launch_bounds__(256) void agent_attn_partial(
    const float* __restrict__ qkv, const float* __restrict__ at,
    float* __restrict__ paccv, float* __restrict__ paccs) {
  const int chunk = blockIdx.x, h = blockIdx.y, bg = blockIdx.z;
  __shared__ float ah[Aa][HD];
  __shared__ float KtF[64 * 64];   // swizzled [jj][slot^(jj&15)]
  __shared__ float Vt[64][68];     // row-major [jj][c], +4 pad
  __shared__ float Pm[Aa][68];     // exp(scores), +4 pad
  const int t = threadIdx.x;

  for (int idx = t; idx < Aa * HD; idx += 256) {
    int a = idx >> 6, c = idx & 63;
    ah[a][c] = at[(size_t)(bg * Aa + a) * Cc + h * HD + c];
  }
  float accv[13];
#pragma unroll
  for (int k = 0; k < 13; ++k) accv[k] = 0.f;
  float accs = 0.f;
  const int jstart = chunk * CHUNK;
  const int jend = min(jstart + CHUNK, Nn);

  for (int j0 = jstart; j0 < jend; j0 += 64) {
    __syncthreads();
    // load K/V tiles (64 rows x 64 ch)
#pragma unroll
    for (int l = 0; l < 4; ++l) {
      int idx = t + l * 256;
      int row = idx >> 4;
      int c4 = (idx & 15) << 2;
      float4 kv = make_float4(0.f, 0.f, 0.f, 0.f), vv = kv;
      int j = j0 + row;
      if (j < jend) {
        const float* p = &qkv[(size_t)(bg * Nn + j) * LDQ + Cc + h * HD + c4];
        kv = *(const float4*)p;
        vv = *(const float4*)(p + Cc);
      }
      int slot = (c4 >> 2) ^ (row & 15);
      *(float4*)&KtF[row * 64 + slot * 4] = kv;
      *(float4*)&Vt[row][c4] = vv;   // row-major: Vt[jj][c]
    }
    __syncthreads();
    // P = exp(scale * ah @ Kt^T), masked beyond jend
    for (int idx = t; idx < Aa * 64; idx += 256) {
      int a = idx >> 6, jj = idx & 63;
      float s = 0.f;
#pragma unroll
      for (int kk = 0; kk < 16; ++kk) {
        float4 a4 = *(const float4*)&ah[a][kk << 2];
        float4 k4 = *(const float4*)&KtF[jj * 64 + ((kk ^ (jj & 15)) << 2)];
        s += a4.x * k4.x + a4.y * k4.y + a4.z * k4.z + a4.w * k4.w;
      }
      Pm[a][jj] = (j0 + jj < jend) ? expf(s * SCALE) : 0.f;
    }
    __syncthreads();
    // accumulate row sums (denominator)
    if (t < Aa) {
      float ss = 0.f;
#pragma unroll
      for (int q = 0; q < 16; ++q) {
        float4 p4 = *(const float4*)&Pm[t][q << 2];
        ss += p4.x + p4.y + p4.z + p4.w;
      }
      accs += ss;
    }
    // accumulate P @ V  (idx = a*64 + c; a wave-uniform, c per-lane;
    // Vt[jj][c] reads: lanes hit consecutive addresses -> conflict-free)
#pragma unroll
    for (int k = 0; k < 13; ++k) {
      int idx = t + k * 256;
      if (idx < Aa * 64) {
        int a = idx >> 6, c = idx & 63;
        float sum = 0.f;
#pragma unroll
        for (int q = 0; q < 16; ++q) {
          float4 p4 = *(const float4*)&Pm[a][q << 2];
          sum += p4.x * Vt[4 * q + 0][c] + p4.y * Vt[4 * q + 1][c] +
                 p4.z * Vt[4 * q + 2][c] + p4.w * Vt[4 * q + 3][c];
        }
        accv[k] += sum;
      }
    }
  }

  const int basev = ((bg * Hh + h) * NCH + chunk) * (Aa * 64);
#pragma unroll
  for (int k = 0; k < 13; ++k) {
    int idx = t + k * 256;
    if (idx < Aa * 64) paccv[basev + idx] = accv[k];
  }
  if (t < Aa) paccs[((bg * Hh + h) * NCH + chunk) * Aa + t] = accs;
}

// ---------------------------------------------------------------------------
// Merge chunk partials -> agent_v[bgh,a,c]
// ---------------------------------------------------------------------------
__global__ __launch_bounds__(256) void merge_agent(
    const float* __restrict__ paccv, const float* __restrict__ paccs,
    float* __restrict__ av) {
  const int bh = blockIdx.x;
  const int t = threadIdx.x;
  for (int idx = t; idx < Aa * HD; idx += 256) {
    int a = idx >> 6;
    float vs = 0.f, ss = 0.f;
#pragma unroll
    for (int ch = 0; ch < NCH; ++ch) {
      vs += paccv[(size_t)((bh * NCH + ch)) * (Aa * 64) + idx];
      ss += paccs[(bh * NCH + ch) * Aa + a];
    }
    av[(size_t)bh * (Aa * HD) + idx] = vs / ss;
  }
}

// ---------------------------------------------------------------------------
// q attention: outp[bg,i,h*64+c] = softmax_a(scale * q_i . ah_a) @ agent_v.
// ---------------------------------------------------------------------------
__global__ __launch_bounds__(256) void q_attn_kernel(
    const float* __restrict__ qkv, const float* __restrict__ at,
    const float* __restrict__ av, float* __restrict__ outp) {
  const int tile = blockIdx.x, h = blockIdx.y, bg = blockIdx.z;
  __shared__ float ahs[Aa][HD];
  __shared__ float avs[Aa][HD];
  const int t = threadIdx.x;
  for (int idx = t; idx < Aa * HD; idx += 256) {
    int a = idx >> 6, c = idx & 63;
    ahs[a][c] = at[(size_t)(bg * Aa + a) * Cc + h * HD + c];
    avs[a][c] = av[(size_t)(bg * Hh + h) * (Aa * HD) + idx];
  }
  __syncthreads();
  const int i = tile * 256 + t;
  if (i >= Nn) return;

  float4 q4[16];
  const float* qrow = &qkv[(size_t)(bg * Nn + i) * LDQ + h * HD];
#pragma unroll
  for (int kk = 0; kk < 16; ++kk) q4[kk] = *(const float4*)&qrow[kk * 4];

  float ssum = 0.f;
  for (int a = 0; a < Aa; ++a) {
    float s = 0.f;
#pragma unroll
    for (int kk = 0; kk < 16; ++kk) {
      float4 a4 = *(const float4*)&ahs[a][kk * 4];
      s += q4[kk].x * a4.x + q4[kk].y * a4.y + q4[kk].z * a4.z + q4[kk].w * a4.w;
    }
    ssum += expf(s * SCALE);
  }
  const float inv = 1.0f / ssum;

  float4 o4[16];
#pragma unroll
  for (int kk = 0; kk < 16; ++kk) o4[kk] = make_float4(0.f, 0.f, 0.f, 0.f);
  for (int a = 0; a < Aa; ++a) {
    float s = 0.f;
#pragma unroll
    for (int kk = 0; kk < 16; ++kk) {
      float4 a4 = *(const float4*)&ahs[a][kk * 4];
      s += q4[kk].x * a4.x + q4[kk].y * a4.y + q4[kk].z * a4.z + q4[kk].w * a4.w;
    }
    float p = expf(s * SCALE) * inv;
#pragma unroll
    for (int kk = 0; kk < 16; ++kk) {
      float4 v4 = *(const float4*)&avs[a][kk * 4];
      o4[kk].x += p * v4.x; o4[kk].y += p * v4.y;
      o4[kk].z += p * v4.z; o4[kk].w += p * v4.w;
    }
  }
  float* orow = &outp[(size_t)(bg * Nn + i) * Cc + h * HD];
#pragma unroll
  for (int kk = 0; kk < 16; ++kk) *(float4*)&orow[kk * 4] = o4[kk];
}

// ---------------------------------------------------------------------------
// Depthwise conv (kernel 3, zero pad) over v[bg, :4096, :], added into outp.
// ---------------------------------------------------------------------------
__global__ __launch_bounds__(256) void dwc_add(
    const float* __restrict__ qkv, const float* __restrict__ w,
    const float* __restrict__ wb, float* __restrict__ outp) {
  const int flat = blockIdx.x * 256 + threadIdx.x;  // per float4
  const int c4 = (flat % 192) * 4;
  const int rest = flat / 192;
  const int i = rest & 4095;
  const int bg = rest >> 12;
  const float* vb = &qkv[(size_t)bg * Nn * LDQ + 2 * Cc + c4];
  const float4 z = make_float4(0.f, 0.f, 0.f, 0.f);
  float4 vm = (i > 0) ? *(const float4*)&vb[(size_t)(i - 1) * LDQ] : z;
  float4 v0 = *(const float4*)&vb[(size_t)i * LDQ];
  float4 vp = (i < 4095) ? *(const float4*)&vb[(size_t)(i + 1) * LDQ] : z;
  float* op = &outp[(size_t)(bg * Nn + i) * Cc + c4];
  float4 o = *(const float4*)op;
  o.x += w[(c4 + 0) * 3] * vm.x + w[(c4 + 0) * 3 + 1] * v0.x + w[(c4 + 0) * 3 + 2] * vp.x + wb[c4 + 0];
  o.y += w[(c4 + 1) * 3] * vm.y + w[(c4 + 1) * 3 + 1] * v0.y + w[(c4 + 1) * 3 + 2] * vp.y + wb[c4 + 1];
  o.z += w[(c4 + 2) * 3] * vm.z + w[(c4 + 2) * 3 + 1] * v0.z + w[(c4 + 2) * 3 + 2] * vp.z + wb[c4 + 2];
  o.w += w[(c4 + 3) * 3] * vm.w + w[(c4 + 3) * 3 + 1] * v0.w + w[(c4 + 3) * 3 + 2] * vp.w + wb[c4 + 3];
  *(float4*)op = o;
}

}  // namespace

extern "C" void kernel_launch(void* const* d_in, const int* in_sizes, int n_in,
                              void* d_out, int out_size, void* d_ws,
                              size_t ws_size, hipStream_t stream) {
  const float* x = (const float*)d_in[0];
  const float* Wqkv = (const float*)d_in[1];
  const float* Wproj = (const float*)d_in[2];
  const float* bproj = (const float*)d_in[3];
  const float* dwcw = (const float*)d_in[4];
  const float* dwcb = (const float*)d_in[5];
  float* out = (float*)d_out;

  // per-batch workspace floats
  const size_t fQkv = (size_t)Nn * LDQ;            // 9,439,488
  const size_t fAt = (size_t)Aa * Cc;              //    37,632
  const size_t fPv = (size_t)Hh * NCH * Aa * 64;   //   301,056
  const size_t fPs = (size_t)Hh * NCH * Aa;        //     4,704
  const size_t fAv = (size_t)Hh * Aa * HD;         //    37,632
  const size_t fOut = (size_t)Nn * Cc;             // 3,146,496
  const size_t perBatch = fQkv + fAt + fPv + fPs + fAv + fOut;  // ~51.9 MB

  int G = (int)(ws_size / (perBatch * sizeof(float)));
  if (G < 1) G = 1;
  if (G > Bb) G = Bb;

  float* ws = (float*)d_ws;
  float* qkv = ws;
  float* at = qkv + fQkv * G;
  float* paccv = at + fAt * G;
  float* paccs = paccv + fPv * G;
  float* av = paccs + fPs * G;
  float* outp = av + fAv * G;

  dim3 blk(256);
  for (int b0 = 0; b0 < Bb; b0 += G) {
    const int Gi = (b0 + G <= Bb) ? G : (Bb - b0);
    const int Mg = Gi * Nn;
    const float* xg = x + (size_t)b0 * Nn * Cc;
    float* outg = out + (size_t)b0 * Nn * Cc;

    // 1) qkv = x_g @ Wqkv
    gemm128<<<dim3(LDQ / 128, (Mg + 127) / 128), blk, 0, stream>>>(
        xg, Wqkv, qkv, nullptr, Mg, Cc, LDQ, LDQ, Cc);
    // 2) agent tokens (adaptive pool of q)
    pool_agents<<<dim3(Gi * Aa), blk, 0, stream>>>(qkv, at);
    // 3) agent attention partials + merge -> agent_v
    agent_attn_partial<<<dim3(NCH, Hh, Gi), blk, 0, stream>>>(qkv, at, paccv,
                                                              paccs);
    merge_agent<<<dim3(Gi * Hh), blk, 0, stream>>>(paccv, paccs, av);
    // 4) q attention -> outp
    q_attn_kernel<<<dim3((Nn + 255) / 256, Hh, Gi), blk, 0, stream>>>(
        qkv, at, av, outp);
    // 5) depthwise conv added into outp
    dwc_add<<<dim3(Gi * 4096 * 192 / 256), blk, 0, stream>>>(qkv, dwcw, dwcb,
                                                             outp);
    // 6) final projection -> out_g
    gemm128<<<dim3(Cc / 128, (Mg + 127) / 128), blk, 0, stream>>>(
        outp, Wproj, outg, bproj, Mg, Cc, Cc, Cc, Cc);
  }
}

// Round 5
// 2066.942 us; speedup vs baseline: 1.4990x; 1.4990x over previous
//
#include <hip/hip_runtime.h>

namespace {

constexpr int Bb = 8;
constexpr int Nn = 4097;
constexpr int Cc = 768;
constexpr int Hh = 12;
constexpr int HD = 64;
constexpr int Aa = 49;
constexpr int LDQ = 3 * Cc;        // 2304 (qkv row stride)
constexpr int NCH = 8;             // j-chunks for agent attention
constexpr int CHUNK = (Nn + NCH - 1) / NCH;  // 513
constexpr float SCALE = 0.125f;    // hd^-0.5
constexpr int KC = 768;            // K of both big GEMMs
constexpr int LDT = 40;            // LDS tile row stride in bf16 (32 + 8 pad)

typedef short s16x8 __attribute__((ext_vector_type(8)));
typedef short s16x4 __attribute__((ext_vector_type(4)));
typedef float f32x4 __attribute__((ext_vector_type(4)));

struct HL { short h, l; };

// Split fp32 into hi (truncated bf16, exact bits) + lo (RNE bf16 of residual).
__device__ inline HL splitbf(float v) {
  unsigned u = __float_as_uint(v);
  HL r;
  r.h = (short)(u >> 16);
  float hf = __uint_as_float(u & 0xffff0000u);
  float lf = v - hf;
  unsigned ul = __float_as_uint(lf);
  r.l = (short)((ul + 0x7fffu + ((ul >> 16) & 1u)) >> 16);
  return r;
}

// ---------------------------------------------------------------------------
// Weight pre-convert: W[K][N] fp32 -> hi/lo [N][K] bf16 (transposed planes).
// ---------------------------------------------------------------------------
__global__ __launch_bounds__(256) void wsplit_t(
    const float* __restrict__ W, short* __restrict__ hi,
    short* __restrict__ lo, int K, int N) {
  int idx = blockIdx.x * 256 + threadIdx.x;
  if (idx >= K * N) return;
  int k = idx / N, n = idx - k * N;
  HL r = splitbf(W[idx]);
  hi[(size_t)n * K + k] = r.h;
  lo[(size_t)n * K + k] = r.l;
}

// ---------------------------------------------------------------------------
// C[M x N] = A[M x KC] @ B (+bias), B given as bf16 split planes [N][KC].
// Tile 128x128, BK=32, 256 threads = 4 waves (2x2), per-wave 64x64 via
// 4x4 frags of mfma_f32_16x16x32_bf16, 3-product split accumulation.
// A split to bf16 hi/lo during LDS staging. N must be a multiple of 128.
// ---------------------------------------------------------------------------
__global__ __launch_bounds__(256) void gemm_mfma_split(
    const float* __restrict__ Am, const short* __restrict__ Bhi,
    const short* __restrict__ Blo, float* __restrict__ Cm,
    const float* __restrict__ bias, int Mr, int ldc) {
  __shared__ __align__(16) short AsH[128 * LDT], AsL[128 * LDT];
  __shared__ __align__(16) short BsH[128 * LDT], BsL[128 * LDT];
  const int t = threadIdx.x;
  const int lane = t & 63;
  const int w = t >> 6;
  const int wr = w >> 1, wc = w & 1;
  const int m0 = blockIdx.y * 128, n0 = blockIdx.x * 128;
  const int l15 = lane & 15, l4 = lane >> 4;

  f32x4 acc[4][4];
#pragma unroll
  for (int m = 0; m < 4; ++m)
#pragma unroll
    for (int n = 0; n < 4; ++n) acc[m][n] = (f32x4){0.f, 0.f, 0.f, 0.f};

  for (int k0 = 0; k0 < KC; k0 += 32) {
    __syncthreads();
    // stage A: 128 rows x 32 k fp32 -> split bf16 planes
#pragma unroll
    for (int l = 0; l < 4; ++l) {
      int idx = t + l * 256;
      int row = idx >> 3;
      int c4 = (idx & 7) << 2;
      float4 v = make_float4(0.f, 0.f, 0.f, 0.f);
      int gr = m0 + row;
      if (gr < Mr) v = *(const float4*)&Am[(size_t)gr * KC + k0 + c4];
      s16x4 hv, lv;
      HL r0 = splitbf(v.x), r1 = splitbf(v.y), r2 = splitbf(v.z),
         r3 = splitbf(v.w);
      hv[0] = r0.h; hv[1] = r1.h; hv[2] = r2.h; hv[3] = r3.h;
      lv[0] = r0.l; lv[1] = r1.l; lv[2] = r2.l; lv[3] = r3.l;
      *(s16x4*)&AsH[row * LDT + c4] = hv;
      *(s16x4*)&AsL[row * LDT + c4] = lv;
    }
    // stage B: 128 rows x 32 k bf16 (already split, [N][KC] row-major)
#pragma unroll
    for (int l = 0; l < 2; ++l) {
      int idx = t + l * 256;
      int row = idx >> 2;
      int seg = (idx & 3) << 3;
      s16x8 bh = *(const s16x8*)&Bhi[(size_t)(n0 + row) * KC + k0 + seg];
      s16x8 bl = *(const s16x8*)&Blo[(size_t)(n0 + row) * KC + k0 + seg];
      *(s16x8*)&BsH[row * LDT + seg] = bh;
      *(s16x8*)&BsL[row * LDT + seg] = bl;
    }
    __syncthreads();

    s16x8 ah[4], al[4], bh[4], bl[4];
#pragma unroll
    for (int m = 0; m < 4; ++m) {
      int r = wr * 64 + m * 16 + l15;
      ah[m] = *(const s16x8*)&AsH[r * LDT + l4 * 8];
      al[m] = *(const s16x8*)&AsL[r * LDT + l4 * 8];
    }
#pragma unroll
    for (int n = 0; n < 4; ++n) {
      int r = wc * 64 + n * 16 + l15;
      bh[n] = *(const s16x8*)&BsH[r * LDT + l4 * 8];
      bl[n] = *(const s16x8*)&BsL[r * LDT + l4 * 8];
    }
#pragma unroll
    for (int m = 0; m < 4; ++m)
#pragma unroll
      for (int n = 0; n < 4; ++n) {
        acc[m][n] = __builtin_amdgcn_mfma_f32_16x16x32_bf16(ah[m], bh[n],
                                                            acc[m][n], 0, 0, 0);
        acc[m][n] = __builtin_amdgcn_mfma_f32_16x16x32_bf16(ah[m], bl[n],
                                                            acc[m][n], 0, 0, 0);
        acc[m][n] = __builtin_amdgcn_mfma_f32_16x16x32_bf16(al[m], bh[n],
                                                            acc[m][n], 0, 0, 0);
      }
  }

  // C/D layout: col = lane&15, row = (lane>>4)*4 + reg
#pragma unroll
  for (int m = 0; m < 4; ++m) {
#pragma unroll
    for (int j = 0; j < 4; ++j) {
      int gr = m0 + wr * 64 + m * 16 + l4 * 4 + j;
      if (gr < Mr) {
#pragma unroll
        for (int n = 0; n < 4; ++n) {
          int gc = n0 + wc * 64 + n * 16 + l15;
          float v = acc[m][n][j];
          if (bias) v += bias[gc];
          Cm[(size_t)gr * ldc + gc] = v;
        }
      }
    }
  }
}

// ---------------------------------------------------------------------------
// Adaptive-pool agents: at[bg,a,c] = mean over q rows [s,e) of q[bg,l,c].
// ---------------------------------------------------------------------------
__global__ __launch_bounds__(256) void pool_agents(
    const float* __restrict__ qkv, float* __restrict__ at) {
  const int ba = blockIdx.x;
  const int bg = ba / Aa, a = ba % Aa;
  const int s = (a * 4096) / 49;
  const int e = ((a + 1) * 4096 + 48) / 49;
  const float w = 1.0f / (float)(e - s);
  const int t = threadIdx.x;
  for (int c = t; c < Cc; c += 256) {
    float sum = 0.f;
    for (int l = s; l < e; ++l)
      sum += qkv[(size_t)(bg * Nn + l) * LDQ + c];
    at[(size_t)(bg * Aa + a) * Cc + c] = sum * w;
  }
}

// ---------------------------------------------------------------------------
// Agent attention (no max-subtraction: scores tiny), partial over a j-chunk:
// paccv[bgh,ch,a,c] = sum_j exp(s)*v,  paccs[bgh,ch,a] = sum_j exp(s).
// K tile slot-XOR swizzled (T2); V tile row-major [jj][c] (+4 pad).
// ---------------------------------------------------------------------------
__global__ __launch_bounds__(256) void agent_attn_partial(
    const float* __restrict__ qkv, const float* __restrict__ at,
    float* __restrict__ paccv, float* __restrict__ paccs) {
  const int chunk = blockIdx.x, h = blockIdx.y, bg = blockIdx.z;
  __shared__ float ah[Aa][HD];
  __shared__ float KtF[64 * 64];   // swizzled [jj][slot^(jj&15)]
  __shared__ float Vt[64][68];     // row-major [jj][c], +4 pad
  __shared__ float Pm[Aa][68];     // exp(scores), +4 pad
  const int t = threadIdx.x;

  for (int idx = t; idx < Aa * HD; idx += 256) {
    int a = idx >> 6, c = idx & 63;
    ah[a][c] = at[(size_t)(bg * Aa + a) * Cc + h * HD + c];
  }
  float accv[13];
#pragma unroll
  for (int k = 0; k < 13; ++k) accv[k] = 0.f;
  float accs = 0.f;
  const int jstart = chunk * CHUNK;
  const int jend = min(jstart + CHUNK, Nn);

  for (int j0 = jstart; j0 < jend; j0 += 64) {
    __syncthreads();
#pragma unroll
    for (int l = 0; l < 4; ++l) {
      int idx = t + l * 256;
      int row = idx >> 4;
      int c4 = (idx & 15) << 2;
      float4 kv = make_float4(0.f, 0.f, 0.f, 0.f), vv = kv;
      int j = j0 + row;
      if (j < jend) {
        const float* p = &qkv[(size_t)(bg * Nn + j) * LDQ + Cc + h * HD + c4];
        kv = *(const float4*)p;
        vv = *(const float4*)(p + Cc);
      }
      int slot = (c4 >> 2) ^ (row & 15);
      *(float4*)&KtF[row * 64 + slot * 4] = kv;
      *(float4*)&Vt[row][c4] = vv;   // row-major: Vt[jj][c]
    }
    __syncthreads();
    for (int idx = t; idx < Aa * 64; idx += 256) {
      int a = idx >> 6, jj = idx & 63;
      float s = 0.f;
#pragma unroll
      for (int kk = 0; kk < 16; ++kk) {
        float4 a4 = *(const float4*)&ah[a][kk << 2];
        float4 k4 = *(const float4*)&KtF[jj * 64 + ((kk ^ (jj & 15)) << 2)];
        s += a4.x * k4.x + a4.y * k4.y + a4.z * k4.z + a4.w * k4.w;
      }
      Pm[a][jj] = (j0 + jj < jend) ? expf(s * SCALE) : 0.f;
    }
    __syncthreads();
    if (t < Aa) {
      float ss = 0.f;
#pragma unroll
      for (int q = 0; q < 16; ++q) {
        float4 p4 = *(const float4*)&Pm[t][q << 2];
        ss += p4.x + p4.y + p4.z + p4.w;
      }
      accs += ss;
    }
#pragma unroll
    for (int k = 0; k < 13; ++k) {
      int idx = t + k * 256;
      if (idx < Aa * 64) {
        int a = idx >> 6, c = idx & 63;
        float sum = 0.f;
#pragma unroll
        for (int q = 0; q < 16; ++q) {
          float4 p4 = *(const float4*)&Pm[a][q << 2];
          sum += p4.x * Vt[4 * q + 0][c] + p4.y * Vt[4 * q + 1][c] +
                 p4.z * Vt[4 * q + 2][c] + p4.w * Vt[4 * q + 3][c];
        }
        accv[k] += sum;
      }
    }
  }

  const int basev = ((bg * Hh + h) * NCH + chunk) * (Aa * 64);
#pragma unroll
  for (int k = 0; k < 13; ++k) {
    int idx = t + k * 256;
    if (idx < Aa * 64) paccv[basev + idx] = accv[k];
  }
  if (t < Aa) paccs[((bg * Hh + h) * NCH + chunk) * Aa + t] = accs;
}

// ---------------------------------------------------------------------------
// Merge chunk partials -> agent_v[bgh,a,c]
// ---------------------------------------------------------------------------
__global__ __launch_bounds__(256) void merge_agent(
    const float* __restrict__ paccv, const float* __restrict__ paccs,
    float* __restrict__ av) {
  const int bh = blockIdx.x;
  const int t = threadIdx.x;
  for (int idx = t; idx < Aa * HD; idx += 256) {
    int a = idx >> 6;
    float vs = 0.f, ss = 0.f;
#pragma unroll
    for (int ch = 0; ch < NCH; ++ch) {
      vs += paccv[(size_t)((bh * NCH + ch)) * (Aa * 64) + idx];
      ss += paccs[(bh * NCH + ch) * Aa + a];
    }
    av[(size_t)bh * (Aa * HD) + idx] = vs / ss;
  }
}

// ---------------------------------------------------------------------------
// q attention: outp[bg,i,h*64+c] = softmax_a(scale * q_i . ah_a) @ agent_v.
// ---------------------------------------------------------------------------
__global__ __launch_bounds__(256) void q_attn_kernel(
    const float* __restrict__ qkv, const float* __restrict__ at,
    const float* __restrict__ av, float* __restrict__ outp) {
  const int tile = blockIdx.x, h = blockIdx.y, bg = blockIdx.z;
  __shared__ float ahs[Aa][HD];
  __shared__ float avs[Aa][HD];
  const int t = threadIdx.x;
  for (int idx = t; idx < Aa * HD; idx += 256) {
    int a = idx >> 6, c = idx & 63;
    ahs[a][c] = at[(size_t)(bg * Aa + a) * Cc + h * HD + c];
    avs[a][c] = av[(size_t)(bg * Hh + h) * (Aa * HD) + idx];
  }
  __syncthreads();
  const int i = tile * 256 + t;
  if (i >= Nn) return;

  float4 q4[16];
  const float* qrow = &qkv[(size_t)(bg * Nn + i) * LDQ + h * HD];
#pragma unroll
  for (int kk = 0; kk < 16; ++kk) q4[kk] = *(const float4*)&qrow[kk * 4];

  float ssum = 0.f;
  for (int a = 0; a < Aa; ++a) {
    float s = 0.f;
#pragma unroll
    for (int kk = 0; kk < 16; ++kk) {
      float4 a4 = *(const float4*)&ahs[a][kk * 4];
      s += q4[kk].x * a4.x + q4[kk].y * a4.y + q4[kk].z * a4.z + q4[kk].w * a4.w;
    }
    ssum += expf(s * SCALE);
  }
  const float inv = 1.0f / ssum;

  float4 o4[16];
#pragma unroll
  for (int kk = 0; kk < 16; ++kk) o4[kk] = make_float4(0.f, 0.f, 0.f, 0.f);
  for (int a = 0; a < Aa; ++a) {
    float s = 0.f;
#pragma unroll
    for (int kk = 0; kk < 16; ++kk) {
      float4 a4 = *(const float4*)&ahs[a][kk * 4];
      s += q4[kk].x * a4.x + q4[kk].y * a4.y + q4[kk].z * a4.z + q4[kk].w * a4.w;
    }
    float p = expf(s * SCALE) * inv;
#pragma unroll
    for (int kk = 0; kk < 16; ++kk) {
      float4 v4 = *(const float4*)&avs[a][kk * 4];
      o4[kk].x += p * v4.x; o4[kk].y += p * v4.y;
      o4[kk].z += p * v4.z; o4[kk].w += p * v4.w;
    }
  }
  float* orow = &outp[(size_t)(bg * Nn + i) * Cc + h * HD];
#pragma unroll
  for (int kk = 0; kk < 16; ++kk) *(float4*)&orow[kk * 4] = o4[kk];
}

// ---------------------------------------------------------------------------
// Depthwise conv (kernel 3, zero pad) over v[bg, :4096, :], added into outp.
// ---------------------------------------------------------------------------
__global__ __launch_bounds__(256) void dwc_add(
    const float* __restrict__ qkv, const float* __restrict__ w,
    const float* __restrict__ wb, float* __restrict__ outp) {
  const int flat = blockIdx.x * 256 + threadIdx.x;  // per float4
  const int c4 = (flat % 192) * 4;
  const int rest = flat / 192;
  const int i = rest & 4095;
  const int bg = rest >> 12;
  const float* vb = &qkv[(size_t)bg * Nn * LDQ + 2 * Cc + c4];
  const float4 z = make_float4(0.f, 0.f, 0.f, 0.f);
  float4 vm = (i > 0) ? *(const float4*)&vb[(size_t)(i - 1) * LDQ] : z;
  float4 v0 = *(const float4*)&vb[(size_t)i * LDQ];
  float4 vp = (i < 4095) ? *(const float4*)&vb[(size_t)(i + 1) * LDQ] : z;
  float* op = &outp[(size_t)(bg * Nn + i) * Cc + c4];
  float4 o = *(const float4*)op;
  o.x += w[(c4 + 0) * 3] * vm.x + w[(c4 + 0) * 3 + 1] * v0.x + w[(c4 + 0) * 3 + 2] * vp.x + wb[c4 + 0];
  o.y += w[(c4 + 1) * 3] * vm.y + w[(c4 + 1) * 3 + 1] * v0.y + w[(c4 + 1) * 3 + 2] * vp.y + wb[c4 + 1];
  o.z += w[(c4 + 2) * 3] * vm.z + w[(c4 + 2) * 3 + 1] * v0.z + w[(c4 + 2) * 3 + 2] * vp.z + wb[c4 + 2];
  o.w += w[(c4 + 3) * 3] * vm.w + w[(c4 + 3) * 3 + 1] * v0.w + w[(c4 + 3) * 3 + 2] * vp.w + wb[c4 + 3];
  *(float4*)op = o;
}

}  // namespace

extern "C" void kernel_launch(void* const* d_in, const int* in_sizes, int n_in,
                              void* d_out, int out_size, void* d_ws,
                              size_t ws_size, hipStream_t stream) {
  const float* x = (const float*)d_in[0];
  const float* Wqkv = (const float*)d_in[1];
  const float* Wproj = (const float*)d_in[2];
  const float* bproj = (const float*)d_in[3];
  const float* dwcw = (const float*)d_in[4];
  const float* dwcb = (const float*)d_in[5];
  float* out = (float*)d_out;

  // --- fixed workspace: split+transposed weight planes (bf16) ---
  char* p = (char*)d_ws;
  short* WtQh = (short*)p; p += (size_t)LDQ * KC * 2;
  short* WtQl = (short*)p; p += (size_t)LDQ * KC * 2;
  short* WtPh = (short*)p; p += (size_t)Cc * KC * 2;
  short* WtPl = (short*)p; p += (size_t)Cc * KC * 2;
  const size_t fixedBytes = (size_t)p - (size_t)d_ws;  // 9,437,184

  // --- per-batch workspace floats ---
  const size_t fQkv = (size_t)Nn * LDQ;
  const size_t fAt = (size_t)Aa * Cc;
  const size_t fPv = (size_t)Hh * NCH * Aa * 64;
  const size_t fPs = (size_t)Hh * NCH * Aa;
  const size_t fAv = (size_t)Hh * Aa * HD;
  const size_t fOut = (size_t)Nn * Cc;
  const size_t perBatch = fQkv + fAt + fPv + fPs + fAv + fOut;  // ~51.9 MB

  size_t remain = (ws_size > fixedBytes) ? (ws_size - fixedBytes) : 0;
  int G = (int)(remain / (perBatch * sizeof(float)));
  if (G < 1) G = 1;
  if (G > Bb) G = Bb;

  float* ws = (float*)p;
  float* qkv = ws;
  float* at = qkv + fQkv * G;
  float* paccv = at + fAt * G;
  float* paccs = paccv + fPv * G;
  float* av = paccs + fPs * G;
  float* outp = av + fAv * G;

  dim3 blk(256);
  // 0) pre-split weights (once per launch; deterministic)
  wsplit_t<<<dim3((KC * LDQ + 255) / 256), blk, 0, stream>>>(Wqkv, WtQh, WtQl,
                                                             KC, LDQ);
  wsplit_t<<<dim3((KC * Cc + 255) / 256), blk, 0, stream>>>(Wproj, WtPh, WtPl,
                                                            KC, Cc);

  for (int b0 = 0; b0 < Bb; b0 += G) {
    const int Gi = (b0 + G <= Bb) ? G : (Bb - b0);
    const int Mg = Gi * Nn;
    const float* xg = x + (size_t)b0 * Nn * Cc;
    float* outg = out + (size_t)b0 * Nn * Cc;

    // 1) qkv = x_g @ Wqkv  (MFMA split-bf16)
    gemm_mfma_split<<<dim3(LDQ / 128, (Mg + 127) / 128), blk, 0, stream>>>(
        xg, WtQh, WtQl, qkv, nullptr, Mg, LDQ);
    // 2) agent tokens (adaptive pool of q)
    pool_agents<<<dim3(Gi * Aa), blk, 0, stream>>>(qkv, at);
    // 3) agent attention partials + merge -> agent_v
    agent_attn_partial<<<dim3(NCH, Hh, Gi), blk, 0, stream>>>(qkv, at, paccv,
                                                              paccs);
    merge_agent<<<dim3(Gi * Hh), blk, 0, stream>>>(paccv, paccs, av);
    // 4) q attention -> outp
    q_attn_kernel<<<dim3((Nn + 255) / 256, Hh, Gi), blk, 0, stream>>>(
        qkv, at, av, outp);
    // 5) depthwise conv added into outp
    dwc_add<<<dim3(Gi * 4096 * 192 / 256), blk, 0, stream>>>(qkv, dwcw, dwcb,
                                                             outp);
    // 6) final projection -> out_g  (MFMA split-bf16, +bias)
    gemm_mfma_split<<<dim3(Cc / 128, (Mg + 127) / 128), blk, 0, stream>>>(
        outp, WtPh, WtPl, outg, bproj, Mg, Cc);
  }
}

// Round 6
// 1820.200 us; speedup vs baseline: 1.7022x; 1.1356x over previous
//
#include <hip/hip_runtime.h>

namespace {

constexpr int Bb = 8;
constexpr int Nn = 4097;
constexpr int Cc = 768;
constexpr int Hh = 12;
constexpr int HD = 64;
constexpr int Aa = 49;
constexpr int LDQ = 3 * Cc;        // 2304 (qkv row stride)
constexpr int NCH = 8;             // j-chunks for agent attention
constexpr int CHUNK = (Nn + NCH - 1) / NCH;  // 513
constexpr float SCALE = 0.125f;    // hd^-0.5
constexpr int KP = 1536;           // packed plane row length (hi 768 | lo 768)

typedef short s16x8 __attribute__((ext_vector_type(8)));
typedef float f32x4 __attribute__((ext_vector_type(4)));

struct HL { short h, l; };

// Split fp32 into hi (truncated bf16, exact bits) + lo (RNE bf16 of residual).
__device__ inline HL splitbf(float v) {
  unsigned u = __float_as_uint(v);
  HL r;
  r.h = (short)(u >> 16);
  float hf = __uint_as_float(u & 0xffff0000u);
  float lf = v - hf;
  unsigned ul = __float_as_uint(lf);
  r.l = (short)((ul + 0x7fffu + ((ul >> 16) & 1u)) >> 16);
  return r;
}

// async global->LDS, 16B per lane (linear dest)
__device__ inline void gload16(const short* g, void* l) {
  __builtin_amdgcn_global_load_lds(
      (const __attribute__((address_space(1))) void*)g,
      (__attribute__((address_space(3))) void*)l, 16, 0, 0);
}

// ---------------------------------------------------------------------------
// Pack activations: src[M][768] fp32 -> dst[M][1536] bf16 = [hi | lo], with
// 16B-chunk XOR swizzle within each 64-elem window: chunk' = chunk ^ (m&7).
// One thread per (m, kc) 8-elem chunk.
// ---------------------------------------------------------------------------
__global__ __launch_bounds__(256) void pack_act(
    const float* __restrict__ src, short* __restrict__ dst, int M) {
  int idx = blockIdx.x * 256 + threadIdx.x;
  if (idx >= M * 96) return;
  int m = idx / 96, kc = idx - m * 96;
  const float* s = src + (size_t)m * 768 + kc * 8;
  float4 v0 = *(const float4*)s;
  float4 v1 = *(const float4*)(s + 4);
  s16x8 hv, lv;
  HL r;
  r = splitbf(v0.x); hv[0] = r.h; lv[0] = r.l;
  r = splitbf(v0.y); hv[1] = r.h; lv[1] = r.l;
  r = splitbf(v0.z); hv[2] = r.h; lv[2] = r.l;
  r = splitbf(v0.w); hv[3] = r.h; lv[3] = r.l;
  r = splitbf(v1.x); hv[4] = r.h; lv[4] = r.l;
  r = splitbf(v1.y); hv[5] = r.h; lv[5] = r.l;
  r = splitbf(v1.z); hv[6] = r.h; lv[6] = r.l;
  r = splitbf(v1.w); hv[7] = r.h; lv[7] = r.l;
  int win = (kc >> 3) * 64;
  int jj = ((kc & 7) ^ (m & 7)) * 8;
  short* d = dst + (size_t)m * KP;
  *(s16x8*)&d[win + jj] = hv;
  *(s16x8*)&d[768 + win + jj] = lv;
}

// ---------------------------------------------------------------------------
// Pack weights: W[768][N] fp32 -> Wpk[N][1536] bf16 = [hi | lo], same swizzle
// keyed by (n&7). Thread per (kc, n), n fastest for coalesced reads.
// ---------------------------------------------------------------------------
__global__ __launch_bounds__(256) void pack_w(
    const float* __restrict__ W, short* __restrict__ Wpk, int N) {
  int idx = blockIdx.x * 256 + threadIdx.x;
  if (idx >= 96 * N) return;
  int kc = idx / N, n = idx - kc * N;
  s16x8 hv, lv;
#pragma unroll
  for (int i = 0; i < 8; ++i) {
    HL r = splitbf(W[(size_t)(kc * 8 + i) * N + n]);
    hv[i] = r.h; lv[i] = r.l;
  }
  int win = (kc >> 3) * 64;
  int jj = ((kc & 7) ^ (n & 7)) * 8;
  short* d = Wpk + (size_t)n * KP;
  *(s16x8*)&d[win + jj] = hv;
  *(s16x8*)&d[768 + win + jj] = lv;
}

// ---------------------------------------------------------------------------
// C[M x N] = A @ B (+bias) on packed planes. 3-term split via K'=2304:
// kt 0-11:(Ah,Bh) 12-23:(Ah,Bl) 24-35:(Al,Bh). 128x128 tile, BK=64, 256 thr,
// 4 waves (2x2), 4x4 mfma_f32_16x16x32_bf16 frags/wave. global_load_lds
// staging (linear LDS, source pre-swizzled); each block loops npb n-tiles.
// ---------------------------------------------------------------------------
__global__ __launch_bounds__(256) void gemm_pk(
    const short* __restrict__ Apk, const short* __restrict__ Bpk,
    float* __restrict__ Cm, const float* __restrict__ bias,
    int Mr, int ldc, int npb) {
  __shared__ __align__(16) short As[128 * 64];
  __shared__ __align__(16) short Bs[128 * 64];
  const int t = threadIdx.x;
  const int lane = t & 63;
  const int w = t >> 6;
  const int wr = w >> 1, wc = w & 1;
  const int l15 = lane & 15, l4 = lane >> 4;
  const int m0 = blockIdx.y * 128;

  for (int ns = 0; ns < npb; ++ns) {
    const int n0 = (blockIdx.x * npb + ns) * 128;
    f32x4 acc[4][4];
#pragma unroll
    for (int mi = 0; mi < 4; ++mi)
#pragma unroll
      for (int ni = 0; ni < 4; ++ni) acc[mi][ni] = (f32x4){0.f, 0.f, 0.f, 0.f};

    for (int kt = 0; kt < 36; ++kt) {
      const int ak = (kt < 12) ? kt * 64
                   : (kt < 24) ? (kt - 12) * 64
                               : 768 + (kt - 24) * 64;
      const int bk = (kt < 12) ? kt * 64
                   : (kt < 24) ? 768 + (kt - 12) * 64
                               : (kt - 24) * 64;
      __syncthreads();
#pragma unroll
      for (int i = 0; i < 4; ++i) {
        const int o = (i * 256 + t) * 16;    // byte offset in 16KB tile
        const int row = o >> 7;
        const int ce = (o & 127) >> 1;       // element col (physical)
        gload16(Apk + (size_t)(m0 + row) * KP + ak + ce, (char*)As + o);
        gload16(Bpk + (size_t)(n0 + row) * KP + bk + ce, (char*)Bs + o);
      }
      __syncthreads();
#pragma unroll
      for (int ks = 0; ks < 2; ++ks) {
        s16x8 af[4], bf[4];
#pragma unroll
        for (int mi = 0; mi < 4; ++mi) {
          int r = wr * 64 + mi * 16 + l15;
          af[mi] = *(const s16x8*)&As[r * 64 + ((((ks << 2) + l4) ^ (l15 & 7)) << 3)];
        }
#pragma unroll
        for (int ni = 0; ni < 4; ++ni) {
          int r = wc * 64 + ni * 16 + l15;
          bf[ni] = *(const s16x8*)&Bs[r * 64 + ((((ks << 2) + l4) ^ (l15 & 7)) << 3)];
        }
#pragma unroll
        for (int mi = 0; mi < 4; ++mi)
#pragma unroll
          for (int ni = 0; ni < 4; ++ni)
            acc[mi][ni] = __builtin_amdgcn_mfma_f32_16x16x32_bf16(
                af[mi], bf[ni], acc[mi][ni], 0, 0, 0);
      }
    }

    // C/D layout: col = lane&15, row = (lane>>4)*4 + reg
#pragma unroll
    for (int mi = 0; mi < 4; ++mi) {
#pragma unroll
      for (int j = 0; j < 4; ++j) {
        int gr = m0 + wr * 64 + mi * 16 + l4 * 4 + j;
        if (gr < Mr) {
#pragma unroll
          for (int ni = 0; ni < 4; ++ni) {
            int gc = n0 + wc * 64 + ni * 16 + l15;
            float v = acc[mi][ni][j];
            if (bias) v += bias[gc];
            Cm[(size_t)gr * ldc + gc] = v;
          }
        }
      }
    }
  }
}

// ---------------------------------------------------------------------------
// Adaptive-pool agents: at[bg,a,c] = mean over q rows [s,e) of q[bg,l,c].
// ---------------------------------------------------------------------------
__global__ __launch_bounds__(256) void pool_agents(
    const float* __restrict__ qkv, float* __restrict__ at) {
  const int ba = blockIdx.x;
  const int bg = ba / Aa, a = ba % Aa;
  const int s = (a * 4096) / 49;
  const int e = ((a + 1) * 4096 + 48) / 49;
  const float w = 1.0f / (float)(e - s);
  const int t = threadIdx.x;
  for (int c = t; c < Cc; c += 256) {
    float sum = 0.f;
    for (int l = s; l < e; ++l)
      sum += qkv[(size_t)(bg * Nn + l) * LDQ + c];
    at[(size_t)(bg * Aa + a) * Cc + c] = sum * w;
  }
}

// ---------------------------------------------------------------------------
// Agent attention (no max-subtraction: scores tiny), partial over a j-chunk:
// paccv[bgh,ch,a,c] = sum_j exp(s)*v,  paccs[bgh,ch,a] = sum_j exp(s).
// K tile slot-XOR swizzled (T2); V tile row-major [jj][c] (+4 pad).
// ---------------------------------------------------------------------------
__global__ __launch_bounds__(256) void agent_attn_partial(
    const float* __restrict__ qkv, const float* __restrict__ at,
    float* __restrict__ paccv, float* __restrict__ paccs) {
  const int chunk = blockIdx.x, h = blockIdx.y, bg = blockIdx.z;
  __shared__ float ah[Aa][HD];
  __shared__ float KtF[64 * 64];   // swizzled [jj][slot^(jj&15)]
  __shared__ float Vt[64][68];     // row-major [jj][c], +4 pad
  __shared__ float Pm[Aa][68];     // exp(scores), +4 pad
  const int t = threadIdx.x;

  for (int idx = t; idx < Aa * HD; idx += 256) {
    int a = idx >> 6, c = idx & 63;
    ah[a][c] = at[(size_t)(bg * Aa + a) * Cc + h * HD + c];
  }
  float accv[13];
#pragma unroll
  for (int k = 0; k < 13; ++k) accv[k] = 0.f;
  float accs = 0.f;
  const int jstart = chunk * CHUNK;
  const int jend = min(jstart + CHUNK, Nn);

  for (int j0 = jstart; j0 < jend; j0 += 64) {
    __syncthreads();
#pragma unroll
    for (int l = 0; l < 4; ++l) {
      int idx = t + l * 256;
      int row = idx >> 4;
      int c4 = (idx & 15) << 2;
      float4 kv = make_float4(0.f, 0.f, 0.f, 0.f), vv = kv;
      int j = j0 + row;
      if (j < jend) {
        const float* p = &qkv[(size_t)(bg * Nn + j) * LDQ + Cc + h * HD + c4];
        kv = *(const float4*)p;
        vv = *(const float4*)(p + Cc);
      }
      int slot = (c4 >> 2) ^ (row & 15);
      *(float4*)&KtF[row * 64 + slot * 4] = kv;
      *(float4*)&Vt[row][c4] = vv;   // row-major: Vt[jj][c]
    }
    __syncthreads();
    for (int idx = t; idx < Aa * 64; idx += 256) {
      int a = idx >> 6, jj = idx & 63;
      float s = 0.f;
#pragma unroll
      for (int kk = 0; kk < 16; ++kk) {
        float4 a4 = *(const float4*)&ah[a][kk << 2];
        float4 k4 = *(const float4*)&KtF[jj * 64 + ((kk ^ (jj & 15)) << 2)];
        s += a4.x * k4.x + a4.y * k4.y + a4.z * k4.z + a4.w * k4.w;
      }
      Pm[a][jj] = (j0 + jj < jend) ? expf(s * SCALE) : 0.f;
    }
    __syncthreads();
    if (t < Aa) {
      float ss = 0.f;
#pragma unroll
      for (int q = 0; q < 16; ++q) {
        float4 p4 = *(const float4*)&Pm[t][q << 2];
        ss += p4.x + p4.y + p4.z + p4.w;
      }
      accs += ss;
    }
#pragma unroll
    for (int k = 0; k < 13; ++k) {
      int idx = t + k * 256;
      if (idx < Aa * 64) {
        int a = idx >> 6, c = idx & 63;
        float sum = 0.f;
#pragma unroll
        for (int q = 0; q < 16; ++q) {
          float4 p4 = *(const float4*)&Pm[a][q << 2];
          sum += p4.x * Vt[4 * q + 0][c] + p4.y * Vt[4 * q + 1][c] +
                 p4.z * Vt[4 * q + 2][c] + p4.w * Vt[4 * q + 3][c];
        }
        accv[k] += sum;
      }
    }
  }

  const int basev = ((bg * Hh + h) * NCH + chunk) * (Aa * 64);
#pragma unroll
  for (int k = 0; k < 13; ++k) {
    int idx = t + k * 256;
    if (idx < Aa * 64) paccv[basev + idx] = accv[k];
  }
  if (t < Aa) paccs[((bg * Hh + h) * NCH + chunk) * Aa + t] = accs;
}

// ---------------------------------------------------------------------------
// Merge chunk partials -> agent_v[bgh,a,c]
// ---------------------------------------------------------------------------
__global__ __launch_bounds__(256) void merge_agent(
    const float* __restrict__ paccv, const float* __restrict__ paccs,
    float* __restrict__ av) {
  const int bh = blockIdx.x;
  const int t = threadIdx.x;
  for (int idx = t; idx < Aa * HD; idx += 256) {
    int a = idx >> 6;
    float vs = 0.f, ss = 0.f;
#pragma unroll
    for (int ch = 0; ch < NCH; ++ch) {
      vs += paccv[(size_t)((bh * NCH + ch)) * (Aa * 64) + idx];
      ss += paccs[(bh * NCH + ch) * Aa + a];
    }
    av[(size_t)bh * (Aa * HD) + idx] = vs / ss;
  }
}

// ---------------------------------------------------------------------------
// q attention: outp[bg,i,h*64+c] = softmax_a(scale * q_i . ah_a) @ agent_v.
// ---------------------------------------------------------------------------
__global__ __launch_bounds__(256) void q_attn_kernel(
    const float* __restrict__ qkv, const float* __restrict__ at,
    const float* __restrict__ av, float* __restrict__ outp) {
  const int tile = blockIdx.x, h = blockIdx.y, bg = blockIdx.z;
  __shared__ float ahs[Aa][HD];
  __shared__ float avs[Aa][HD];
  const int t = threadIdx.x;
  for (int idx = t; idx < Aa * HD; idx += 256) {
    int a = idx >> 6, c = idx & 63;
    ahs[a][c] = at[(size_t)(bg * Aa + a) * Cc + h * HD + c];
    avs[a][c] = av[(size_t)(bg * Hh + h) * (Aa * HD) + idx];
  }
  __syncthreads();
  const int i = tile * 256 + t;
  if (i >= Nn) return;

  float4 q4[16];
  const float* qrow = &qkv[(size_t)(bg * Nn + i) * LDQ + h * HD];
#pragma unroll
  for (int kk = 0; kk < 16; ++kk) q4[kk] = *(const float4*)&qrow[kk * 4];

  float ssum = 0.f;
  for (int a = 0; a < Aa; ++a) {
    float s = 0.f;
#pragma unroll
    for (int kk = 0; kk < 16; ++kk) {
      float4 a4 = *(const float4*)&ahs[a][kk * 4];
      s += q4[kk].x * a4.x + q4[kk].y * a4.y + q4[kk].z * a4.z + q4[kk].w * a4.w;
    }
    ssum += expf(s * SCALE);
  }
  const float inv = 1.0f / ssum;

  float4 o4[16];
#pragma unroll
  for (int kk = 0; kk < 16; ++kk) o4[kk] = make_float4(0.f, 0.f, 0.f, 0.f);
  for (int a = 0; a < Aa; ++a) {
    float s = 0.f;
#pragma unroll
    for (int kk = 0; kk < 16; ++kk) {
      float4 a4 = *(const float4*)&ahs[a][kk * 4];
      s += q4[kk].x * a4.x + q4[kk].y * a4.y + q4[kk].z * a4.z + q4[kk].w * a4.w;
    }
    float p = expf(s * SCALE) * inv;
#pragma unroll
    for (int kk = 0; kk < 16; ++kk) {
      float4 v4 = *(const float4*)&avs[a][kk * 4];
      o4[kk].x += p * v4.x; o4[kk].y += p * v4.y;
      o4[kk].z += p * v4.z; o4[kk].w += p * v4.w;
    }
  }
  float* orow = &outp[(size_t)(bg * Nn + i) * Cc + h * HD];
#pragma unroll
  for (int kk = 0; kk < 16; ++kk) *(float4*)&orow[kk * 4] = o4[kk];
}

// ---------------------------------------------------------------------------
// Depthwise conv (kernel 3, zero pad) over v[bg, :4096, :], added into outp.
// ---------------------------------------------------------------------------
__global__ __launch_bounds__(256) void dwc_add(
    const float* __restrict__ qkv, const float* __restrict__ w,
    const float* __restrict__ wb, float* __restrict__ outp) {
  const int flat = blockIdx.x * 256 + threadIdx.x;  // per float4
  const int c4 = (flat % 192) * 4;
  const int rest = flat / 192;
  const int i = rest & 4095;
  const int bg = rest >> 12;
  const float* vb = &qkv[(size_t)bg * Nn * LDQ + 2 * Cc + c4];
  const float4 z = make_float4(0.f, 0.f, 0.f, 0.f);
  float4 vm = (i > 0) ? *(const float4*)&vb[(size_t)(i - 1) * LDQ] : z;
  float4 v0 = *(const float4*)&vb[(size_t)i * LDQ];
  float4 vp = (i < 4095) ? *(const float4*)&vb[(size_t)(i + 1) * LDQ] : z;
  float* op = &outp[(size_t)(bg * Nn + i) * Cc + c4];
  float4 o = *(const float4*)op;
  o.x += w[(c4 + 0) * 3] * vm.x + w[(c4 + 0) * 3 + 1] * v0.x + w[(c4 + 0) * 3 + 2] * vp.x + wb[c4 + 0];
  o.y += w[(c4 + 1) * 3] * vm.y + w[(c4 + 1) * 3 + 1] * v0.y + w[(c4 + 1) * 3 + 2] * vp.y + wb[c4 + 1];
  o.z += w[(c4 + 2) * 3] * vm.z + w[(c4 + 2) * 3 + 1] * v0.z + w[(c4 + 2) * 3 + 2] * vp.z + wb[c4 + 2];
  o.w += w[(c4 + 3) * 3] * vm.w + w[(c4 + 3) * 3 + 1] * v0.w + w[(c4 + 3) * 3 + 2] * vp.w + wb[c4 + 3];
  *(float4*)op = o;
}

}  // namespace

extern "C" void kernel_launch(void* const* d_in, const int* in_sizes, int n_in,
                              void* d_out, int out_size, void* d_ws,
                              size_t ws_size, hipStream_t stream) {
  const float* x = (const float*)d_in[0];
  const float* Wqkv = (const float*)d_in[1];
  const float* Wproj = (const float*)d_in[2];
  const float* bproj = (const float*)d_in[3];
  const float* dwcw = (const float*)d_in[4];
  const float* dwcb = (const float*)d_in[5];
  float* out = (float*)d_out;

  // --- fixed workspace: packed weight planes ---
  char* p = (char*)d_ws;
  short* WQpk = (short*)p; p += (size_t)LDQ * KP * 2;   // 7,077,888 B
  short* WPpk = (short*)p; p += (size_t)Cc * KP * 2;    // 2,359,296 B
  const size_t fixedBytes = (size_t)p - (size_t)d_ws;

  // --- choose group size G (largest that fits) ---
  auto bytesFor = [&](int G) -> size_t {
    size_t Mg = (size_t)G * Nn;
    size_t Mpad = ((Mg + 127) / 128) * 128;
    size_t fl = Mg * LDQ + Mg * Cc +                       // qkv + outp
                (size_t)G * (Aa * Cc + Hh * NCH * Aa * 64 + Hh * NCH * Aa +
                             Hh * Aa * HD);
    return fixedBytes + fl * 4 + Mpad * KP * 2;            // + Apk/Opk
  };
  int G = 1;
  for (int g = Bb; g >= 1; --g) {
    if (bytesFor(g) <= ws_size) { G = g; break; }
  }

  const size_t MgMax = (size_t)G * Nn;
  const size_t Mpad = ((MgMax + 127) / 128) * 128;
  float* qkv = (float*)p;
  float* outp = qkv + MgMax * LDQ;
  float* at = outp + MgMax * Cc;
  float* paccv = at + (size_t)G * Aa * Cc;
  float* paccs = paccv + (size_t)G * Hh * NCH * Aa * 64;
  float* av = paccs + (size_t)G * Hh * NCH * Aa;
  short* Apk = (short*)(av + (size_t)G * Hh * Aa * HD);   // aliased as Opk

  dim3 blk(256);
  // 0) pack weights (once per launch; deterministic)
  pack_w<<<dim3((96 * LDQ + 255) / 256), blk, 0, stream>>>(Wqkv, WQpk, LDQ);
  pack_w<<<dim3((96 * Cc + 255) / 256), blk, 0, stream>>>(Wproj, WPpk, Cc);

  for (int b0 = 0; b0 < Bb; b0 += G) {
    const int Gi = (b0 + G <= Bb) ? G : (Bb - b0);
    const int Mg = Gi * Nn;
    const int Mtiles = (Mg + 127) / 128;
    const float* xg = x + (size_t)b0 * Nn * Cc;
    float* outg = out + (size_t)b0 * Nn * Cc;

    // 1) pack x -> Apk, then qkv = x @ Wqkv (packed MFMA GEMM)
    pack_act<<<dim3((Mg * 96 + 255) / 256), blk, 0, stream>>>(xg, Apk, Mg);
    gemm_pk<<<dim3(6, Mtiles), blk, 0, stream>>>(Apk, WQpk, qkv, nullptr, Mg,
                                                 LDQ, 3);
    // 2) agent tokens (adaptive pool of q)
    pool_agents<<<dim3(Gi * Aa), blk, 0, stream>>>(qkv, at);
    // 3) agent attention partials + merge -> agent_v
    agent_attn_partial<<<dim3(NCH, Hh, Gi), blk, 0, stream>>>(qkv, at, paccv,
                                                              paccs);
    merge_agent<<<dim3(Gi * Hh), blk, 0, stream>>>(paccv, paccs, av);
    // 4) q attention -> outp
    q_attn_kernel<<<dim3((Nn + 255) / 256, Hh, Gi), blk, 0, stream>>>(
        qkv, at, av, outp);
    // 5) depthwise conv added into outp
    dwc_add<<<dim3(Gi * 4096 * 192 / 256), blk, 0, stream>>>(qkv, dwcw, dwcb,
                                                             outp);
    // 6) pack outp -> Opk(=Apk), final projection -> out_g (+bias)
    pack_act<<<dim3((Mg * 96 + 255) / 256), blk, 0, stream>>>(outp, Apk, Mg);
    gemm_pk<<<dim3(6, Mtiles), blk, 0, stream>>>(Apk, WPpk, outg, bproj, Mg,
                                                 Cc, 1);
  }
}

// Round 7
// 1620.578 us; speedup vs baseline: 1.9118x; 1.1232x over previous
//
#include <hip/hip_runtime.h>

namespace {

constexpr int Bb = 8;
constexpr int Nn = 4097;
constexpr int Cc = 768;
constexpr int Hh = 12;
constexpr int HD = 64;
constexpr int Aa = 49;
constexpr int LDQ = 3 * Cc;        // 2304 (qkv row stride)
constexpr int NCH = 8;             // j-chunks for agent attention
constexpr int CHUNK = (Nn + NCH - 1) / NCH;  // 513
constexpr float SCALE = 0.125f;    // hd^-0.5
constexpr int KP = 1536;           // packed plane row length (hi 768 | lo 768)

typedef short s16x8 __attribute__((ext_vector_type(8)));
typedef float f32x4 __attribute__((ext_vector_type(4)));

struct HL { short h, l; };

// Split fp32 into hi (truncated bf16, exact bits) + lo (RNE bf16 of residual).
__device__ inline HL splitbf(float v) {
  unsigned u = __float_as_uint(v);
  HL r;
  r.h = (short)(u >> 16);
  float hf = __uint_as_float(u & 0xffff0000u);
  float lf = v - hf;
  unsigned ul = __float_as_uint(lf);
  r.l = (short)((ul + 0x7fffu + ((ul >> 16) & 1u)) >> 16);
  return r;
}

// async global->LDS, 16B per lane (linear dest)
__device__ inline void gload16(const short* g, void* l) {
  __builtin_amdgcn_global_load_lds(
      (const __attribute__((address_space(1))) void*)g,
      (__attribute__((address_space(3))) void*)l, 16, 0, 0);
}

// ---------------------------------------------------------------------------
// Pack activations: src[M][768] fp32 -> dst[M][1536] bf16 = [hi | lo], with
// 16B-chunk XOR swizzle within each 64-elem window: chunk' = chunk ^ (m&7).
// ---------------------------------------------------------------------------
__global__ __launch_bounds__(256) void pack_act(
    const float* __restrict__ src, short* __restrict__ dst, int M) {
  int idx = blockIdx.x * 256 + threadIdx.x;
  if (idx >= M * 96) return;
  int m = idx / 96, kc = idx - m * 96;
  const float* s = src + (size_t)m * 768 + kc * 8;
  float4 v0 = *(const float4*)s;
  float4 v1 = *(const float4*)(s + 4);
  s16x8 hv, lv;
  HL r;
  r = splitbf(v0.x); hv[0] = r.h; lv[0] = r.l;
  r = splitbf(v0.y); hv[1] = r.h; lv[1] = r.l;
  r = splitbf(v0.z); hv[2] = r.h; lv[2] = r.l;
  r = splitbf(v0.w); hv[3] = r.h; lv[3] = r.l;
  r = splitbf(v1.x); hv[4] = r.h; lv[4] = r.l;
  r = splitbf(v1.y); hv[5] = r.h; lv[5] = r.l;
  r = splitbf(v1.z); hv[6] = r.h; lv[6] = r.l;
  r = splitbf(v1.w); hv[7] = r.h; lv[7] = r.l;
  int win = (kc >> 3) * 64;
  int jj = ((kc & 7) ^ (m & 7)) * 8;
  short* d = dst + (size_t)m * KP;
  *(s16x8*)&d[win + jj] = hv;
  *(s16x8*)&d[768 + win + jj] = lv;
}

// ---------------------------------------------------------------------------
// Pack weights: W[768][N] fp32 -> Wpk[N][1536] bf16 = [hi | lo], same swizzle
// keyed by (n&7).
// ---------------------------------------------------------------------------
__global__ __launch_bounds__(256) void pack_w(
    const float* __restrict__ W, short* __restrict__ Wpk, int N) {
  int idx = blockIdx.x * 256 + threadIdx.x;
  if (idx >= 96 * N) return;
  int kc = idx / N, n = idx - kc * N;
  s16x8 hv, lv;
#pragma unroll
  for (int i = 0; i < 8; ++i) {
    HL r = splitbf(W[(size_t)(kc * 8 + i) * N + n]);
    hv[i] = r.h; lv[i] = r.l;
  }
  int win = (kc >> 3) * 64;
  int jj = ((kc & 7) ^ (n & 7)) * 8;
  short* d = Wpk + (size_t)n * KP;
  *(s16x8*)&d[win + jj] = hv;
  *(s16x8*)&d[768 + win + jj] = lv;
}

// ---------------------------------------------------------------------------
// C[M x N] = A @ B (+bias) on packed planes. Per 64-K-chunk, stage all four
// planes (AsH/AsL/BsH/BsL, 64KB LDS), then 3 split products x 2 sub-K x 4x4
// frags = 96 mfma_f32_16x16x32_bf16 per barrier pair. 12 kt iterations.
// Grid = 1D, bijective XCD swizzle (m204), logical = mt*nch + nc (n fastest
// -> all n-tiles of an M-panel co-XCD -> A served from L2).
// ---------------------------------------------------------------------------
__global__ __launch_bounds__(256) void gemm_pk2(
    const short* __restrict__ Apk, const short* __restrict__ Bpk,
    float* __restrict__ Cm, const float* __restrict__ bias,
    int Mr, int ldc, int nch, int nwg) {
  __shared__ __align__(16) short AsH[128 * 64], AsL[128 * 64];
  __shared__ __align__(16) short BsH[128 * 64], BsL[128 * 64];
  const int t = threadIdx.x;
  const int lane = t & 63;
  const int w = t >> 6;
  const int wr = w >> 1, wc = w & 1;
  const int l15 = lane & 15, l4 = lane >> 4;

  // bijective XCD swizzle: XCD (j&7) owns a contiguous logical range
  const int j = blockIdx.x;
  const int q = nwg >> 3, r = nwg & 7;
  const int xcd = j & 7, pos = j >> 3;
  const int logical =
      (xcd < r ? xcd * (q + 1) : r * (q + 1) + (xcd - r) * q) + pos;
  const int mt = logical / nch, nc = logical - mt * nch;
  const int m0 = mt * 128, n0 = nc * 128;

  f32x4 acc[4][4];
#pragma unroll
  for (int mi = 0; mi < 4; ++mi)
#pragma unroll
    for (int ni = 0; ni < 4; ++ni) acc[mi][ni] = (f32x4){0.f, 0.f, 0.f, 0.f};

  for (int kt = 0; kt < 12; ++kt) {
    const short* Ab = Apk + (size_t)m0 * KP + kt * 64;
    const short* Bt = Bpk + (size_t)n0 * KP + kt * 64;
    __syncthreads();
#pragma unroll
    for (int i = 0; i < 4; ++i) {
      const int o = (i * 256 + t) * 16;   // byte offset in 16KB plane
      const int row = o >> 7;
      const int ce = (o & 127) >> 1;      // element col (physical)
      gload16(Ab + (size_t)row * KP + ce, (char*)AsH + o);
      gload16(Ab + (size_t)row * KP + 768 + ce, (char*)AsL + o);
      gload16(Bt + (size_t)row * KP + ce, (char*)BsH + o);
      gload16(Bt + (size_t)row * KP + 768 + ce, (char*)BsL + o);
    }
    __syncthreads();
#pragma unroll
    for (int ks = 0; ks < 2; ++ks) {
      s16x8 ah[4], al[4], bh[4], bl[4];
#pragma unroll
      for (int mi = 0; mi < 4; ++mi) {
        int rr = wr * 64 + mi * 16 + l15;
        int off = rr * 64 + ((((ks << 2) + l4) ^ (l15 & 7)) << 3);
        ah[mi] = *(const s16x8*)&AsH[off];
        al[mi] = *(const s16x8*)&AsL[off];
      }
#pragma unroll
      for (int ni = 0; ni < 4; ++ni) {
        int rr = wc * 64 + ni * 16 + l15;
        int off = rr * 64 + ((((ks << 2) + l4) ^ (l15 & 7)) << 3);
        bh[ni] = *(const s16x8*)&BsH[off];
        bl[ni] = *(const s16x8*)&BsL[off];
      }
#pragma unroll
      for (int mi = 0; mi < 4; ++mi)
#pragma unroll
        for (int ni = 0; ni < 4; ++ni) {
          acc[mi][ni] = __builtin_amdgcn_mfma_f32_16x16x32_bf16(
              ah[mi], bh[ni], acc[mi][ni], 0, 0, 0);
          acc[mi][ni] = __builtin_amdgcn_mfma_f32_16x16x32_bf16(
              ah[mi], bl[ni], acc[mi][ni], 0, 0, 0);
          acc[mi][ni] = __builtin_amdgcn_mfma_f32_16x16x32_bf16(
              al[mi], bh[ni], acc[mi][ni], 0, 0, 0);
        }
    }
  }

  // C/D layout: col = lane&15, row = (lane>>4)*4 + reg
#pragma unroll
  for (int mi = 0; mi < 4; ++mi) {
#pragma unroll
    for (int jr = 0; jr < 4; ++jr) {
      int gr = m0 + wr * 64 + mi * 16 + l4 * 4 + jr;
      if (gr < Mr) {
#pragma unroll
        for (int ni = 0; ni < 4; ++ni) {
          int gc = n0 + wc * 64 + ni * 16 + l15;
          float v = acc[mi][ni][jr];
          if (bias) v += bias[gc];
          Cm[(size_t)gr * ldc + gc] = v;
        }
      }
    }
  }
}

// ---------------------------------------------------------------------------
// Adaptive-pool agents: at[bg,a,c] = mean over q rows [s,e) of q[bg,l,c].
// ---------------------------------------------------------------------------
__global__ __launch_bounds__(256) void pool_agents(
    const float* __restrict__ qkv, float* __restrict__ at) {
  const int ba = blockIdx.x;
  const int bg = ba / Aa, a = ba % Aa;
  const int s = (a * 4096) / 49;
  const int e = ((a + 1) * 4096 + 48) / 49;
  const float w = 1.0f / (float)(e - s);
  const int t = threadIdx.x;
  for (int c = t; c < Cc; c += 256) {
    float sum = 0.f;
    for (int l = s; l < e; ++l)
      sum += qkv[(size_t)(bg * Nn + l) * LDQ + c];
    at[(size_t)(bg * Aa + a) * Cc + c] = sum * w;
  }
}

// ---------------------------------------------------------------------------
// Agent attention (no max-subtraction: scores tiny), partial over a j-chunk:
// paccv[bgh,ch,a,c] = sum_j exp(s)*v,  paccs[bgh,ch,a] = sum_j exp(s).
// K tile slot-XOR swizzled (T2); V tile row-major [jj][c] (+4 pad).
// ---------------------------------------------------------------------------
__global__ __launch_bounds__(256) void agent_attn_partial(
    const float* __restrict__ qkv, const float* __restrict__ at,
    float* __restrict__ paccv, float* __restrict__ paccs) {
  const int chunk = blockIdx.x, h = blockIdx.y, bg = blockIdx.z;
  __shared__ float ah[Aa][HD];
  __shared__ float KtF[64 * 64];   // swizzled [jj][slot^(jj&15)]
  __shared__ float Vt[64][68];     // row-major [jj][c], +4 pad
  __shared__ float Pm[Aa][68];     // exp(scores), +4 pad
  const int t = threadIdx.x;

  for (int idx = t; idx < Aa * HD; idx += 256) {
    int a = idx >> 6, c = idx & 63;
    ah[a][c] = at[(size_t)(bg * Aa + a) * Cc + h * HD + c];
  }
  float accv[13];
#pragma unroll
  for (int k = 0; k < 13; ++k) accv[k] = 0.f;
  float accs = 0.f;
  const int jstart = chunk * CHUNK;
  const int jend = min(jstart + CHUNK, Nn);

  for (int j0 = jstart; j0 < jend; j0 += 64) {
    __syncthreads();
#pragma unroll
    for (int l = 0; l < 4; ++l) {
      int idx = t + l * 256;
      int row = idx >> 4;
      int c4 = (idx & 15) << 2;
      float4 kv = make_float4(0.f, 0.f, 0.f, 0.f), vv = kv;
      int j = j0 + row;
      if (j < jend) {
        const float* p = &qkv[(size_t)(bg * Nn + j) * LDQ + Cc + h * HD + c4];
        kv = *(const float4*)p;
        vv = *(const float4*)(p + Cc);
      }
      int slot = (c4 >> 2) ^ (row & 15);
      *(float4*)&KtF[row * 64 + slot * 4] = kv;
      *(float4*)&Vt[row][c4] = vv;   // row-major: Vt[jj][c]
    }
    __syncthreads();
    for (int idx = t; idx < Aa * 64; idx += 256) {
      int a = idx >> 6, jj = idx & 63;
      float s = 0.f;
#pragma unroll
      for (int kk = 0; kk < 16; ++kk) {
        float4 a4 = *(const float4*)&ah[a][kk << 2];
        float4 k4 = *(const float4*)&KtF[jj * 64 + ((kk ^ (jj & 15)) << 2)];
        s += a4.x * k4.x + a4.y * k4.y + a4.z * k4.z + a4.w * k4.w;
      }
      Pm[a][jj] = (j0 + jj < jend) ? expf(s * SCALE) : 0.f;
    }
    __syncthreads();
    if (t < Aa) {
      float ss = 0.f;
#pragma unroll
      for (int q = 0; q < 16; ++q) {
        float4 p4 = *(const float4*)&Pm[t][q << 2];
        ss += p4.x + p4.y + p4.z + p4.w;
      }
      accs += ss;
    }
#pragma unroll
    for (int k = 0; k < 13; ++k) {
      int idx = t + k * 256;
      if (idx < Aa * 64) {
        int a = idx >> 6, c = idx & 63;
        float sum = 0.f;
#pragma unroll
        for (int q = 0; q < 16; ++q) {
          float4 p4 = *(const float4*)&Pm[a][q << 2];
          sum += p4.x * Vt[4 * q + 0][c] + p4.y * Vt[4 * q + 1][c] +
                 p4.z * Vt[4 * q + 2][c] + p4.w * Vt[4 * q + 3][c];
        }
        accv[k] += sum;
      }
    }
  }

  const int basev = ((bg * Hh + h) * NCH + chunk) * (Aa * 64);
#pragma unroll
  for (int k = 0; k < 13; ++k) {
    int idx = t + k * 256;
    if (idx < Aa * 64) paccv[basev + idx] = accv[k];
  }
  if (t < Aa) paccs[((bg * Hh + h) * NCH + chunk) * Aa + t] = accs;
}

// ---------------------------------------------------------------------------
// Merge chunk partials -> agent_v[bgh,a,c]
// ---------------------------------------------------------------------------
__global__ __launch_bounds__(256) void merge_agent(
    const float* __restrict__ paccv, const float* __restrict__ paccs,
    float* __restrict__ av) {
  const int bh = blockIdx.x;
  const int t = threadIdx.x;
  for (int idx = t; idx < Aa * HD; idx += 256) {
    int a = idx >> 6;
    float vs = 0.f, ss = 0.f;
#pragma unroll
    for (int ch = 0; ch < NCH; ++ch) {
      vs += paccv[(size_t)((bh * NCH + ch)) * (Aa * 64) + idx];
      ss += paccs[(bh * NCH + ch) * Aa + a];
    }
    av[(size_t)bh * (Aa * HD) + idx] = vs / ss;
  }
}

// ---------------------------------------------------------------------------
// q attention: outp[bg,i,h*64+c] = softmax_a(scale * q_i . ah_a) @ agent_v.
// ---------------------------------------------------------------------------
__global__ __launch_bounds__(256) void q_attn_kernel(
    const float* __restrict__ qkv, const float* __restrict__ at,
    const float* __restrict__ av, float* __restrict__ outp) {
  const int tile = blockIdx.x, h = blockIdx.y, bg = blockIdx.z;
  __shared__ float ahs[Aa][HD];
  __shared__ float avs[Aa][HD];
  const int t = threadIdx.x;
  for (int idx = t; idx < Aa * HD; idx += 256) {
    int a = idx >> 6, c = idx & 63;
    ahs[a][c] = at[(size_t)(bg * Aa + a) * Cc + h * HD + c];
    avs[a][c] = av[(size_t)(bg * Hh + h) * (Aa * HD) + idx];
  }
  __syncthreads();
  const int i = tile * 256 + t;
  if (i >= Nn) return;

  float4 q4[16];
  const float* qrow = &qkv[(size_t)(bg * Nn + i) * LDQ + h * HD];
#pragma unroll
  for (int kk = 0; kk < 16; ++kk) q4[kk] = *(const float4*)&qrow[kk * 4];

  float ssum = 0.f;
  for (int a = 0; a < Aa; ++a) {
    float s = 0.f;
#pragma unroll
    for (int kk = 0; kk < 16; ++kk) {
      float4 a4 = *(const float4*)&ahs[a][kk * 4];
      s += q4[kk].x * a4.x + q4[kk].y * a4.y + q4[kk].z * a4.z + q4[kk].w * a4.w;
    }
    ssum += expf(s * SCALE);
  }
  const float inv = 1.0f / ssum;

  float4 o4[16];
#pragma unroll
  for (int kk = 0; kk < 16; ++kk) o4[kk] = make_float4(0.f, 0.f, 0.f, 0.f);
  for (int a = 0; a < Aa; ++a) {
    float s = 0.f;
#pragma unroll
    for (int kk = 0; kk < 16; ++kk) {
      float4 a4 = *(const float4*)&ahs[a][kk * 4];
      s += q4[kk].x * a4.x + q4[kk].y * a4.y + q4[kk].z * a4.z + q4[kk].w * a4.w;
    }
    float p = expf(s * SCALE) * inv;
#pragma unroll
    for (int kk = 0; kk < 16; ++kk) {
      float4 v4 = *(const float4*)&avs[a][kk * 4];
      o4[kk].x += p * v4.x; o4[kk].y += p * v4.y;
      o4[kk].z += p * v4.z; o4[kk].w += p * v4.w;
    }
  }
  float* orow = &outp[(size_t)(bg * Nn + i) * Cc + h * HD];
#pragma unroll
  for (int kk = 0; kk < 16; ++kk) *(float4*)&orow[kk * 4] = o4[kk];
}

// ---------------------------------------------------------------------------
// Fused: dwc(v) added to outp rows (<4096), then split+pack to Opk planes.
// One thread per (m, kc) 8-channel chunk, same layout as pack_act.
// ---------------------------------------------------------------------------
__global__ __launch_bounds__(256) void dwc_pack(
    const float* __restrict__ outp, const float* __restrict__ qkv,
    const float* __restrict__ w, const float* __restrict__ wb,
    short* __restrict__ Opk, int Mg) {
  int idx = blockIdx.x * 256 + threadIdx.x;
  if (idx >= Mg * 96) return;
  int m = idx / 96, kc = idx - m * 96;
  int bg = m / Nn, i = m - bg * Nn;
  const float* s = outp + (size_t)m * 768 + kc * 8;
  float val[8];
  float4 o0 = *(const float4*)s;
  float4 o1 = *(const float4*)(s + 4);
  val[0] = o0.x; val[1] = o0.y; val[2] = o0.z; val[3] = o0.w;
  val[4] = o1.x; val[5] = o1.y; val[6] = o1.z; val[7] = o1.w;

  if (i < Nn - 1) {
    const int c0 = kc * 8;
    const float* vb = &qkv[((size_t)bg * Nn + i) * LDQ + 2 * Cc + c0];
    const float4 z = make_float4(0.f, 0.f, 0.f, 0.f);
    float4 vm0 = (i > 0) ? *(const float4*)(vb - LDQ) : z;
    float4 vm1 = (i > 0) ? *(const float4*)(vb - LDQ + 4) : z;
    float4 v00 = *(const float4*)vb;
    float4 v01 = *(const float4*)(vb + 4);
    float4 vp0 = (i < 4095) ? *(const float4*)(vb + LDQ) : z;
    float4 vp1 = (i < 4095) ? *(const float4*)(vb + LDQ + 4) : z;
    float vm[8] = {vm0.x, vm0.y, vm0.z, vm0.w, vm1.x, vm1.y, vm1.z, vm1.w};
    float v0[8] = {v00.x, v00.y, v00.z, v00.w, v01.x, v01.y, v01.z, v01.w};
    float vp[8] = {vp0.x, vp0.y, vp0.z, vp0.w, vp1.x, vp1.y, vp1.z, vp1.w};
#pragma unroll
    for (int c = 0; c < 8; ++c) {
      val[c] += w[(c0 + c) * 3] * vm[c] + w[(c0 + c) * 3 + 1] * v0[c] +
                w[(c0 + c) * 3 + 2] * vp[c] + wb[c0 + c];
    }
  }

  s16x8 hv, lv;
#pragma unroll
  for (int c = 0; c < 8; ++c) {
    HL r = splitbf(val[c]);
    hv[c] = r.h; lv[c] = r.l;
  }
  int win = (kc >> 3) * 64;
  int jj = ((kc & 7) ^ (m & 7)) * 8;
  short* d = Opk + (size_t)m * KP;
  *(s16x8*)&d[win + jj] = hv;
  *(s16x8*)&d[768 + win + jj] = lv;
}

}  // namespace

extern "C" void kernel_launch(void* const* d_in, const int* in_sizes, int n_in,
                              void* d_out, int out_size, void* d_ws,
                              size_t ws_size, hipStream_t stream) {
  const float* x = (const float*)d_in[0];
  const float* Wqkv = (const float*)d_in[1];
  const float* Wproj = (const float*)d_in[2];
  const float* bproj = (const float*)d_in[3];
  const float* dwcw = (const float*)d_in[4];
  const float* dwcb = (const float*)d_in[5];
  float* out = (float*)d_out;

  // --- fixed workspace: packed weight planes ---
  char* p = (char*)d_ws;
  short* WQpk = (short*)p; p += (size_t)LDQ * KP * 2;   // 7,077,888 B
  short* WPpk = (short*)p; p += (size_t)Cc * KP * 2;    // 2,359,296 B
  const size_t fixedBytes = (size_t)p - (size_t)d_ws;

  // --- choose group size G (largest that fits) ---
  auto bytesFor = [&](int G) -> size_t {
    size_t Mg = (size_t)G * Nn;
    size_t Mpad = ((Mg + 127) / 128) * 128;
    size_t fl = Mg * LDQ + Mg * Cc +                       // qkv + outp
                (size_t)G * (Aa * Cc + Hh * NCH * Aa * 64 + Hh * NCH * Aa +
                             Hh * Aa * HD);
    return fixedBytes + fl * 4 + Mpad * KP * 2;            // + Apk/Opk
  };
  int G = 1;
  for (int g = Bb; g >= 1; --g) {
    if (bytesFor(g) <= ws_size) { G = g; break; }
  }

  const size_t MgMax = (size_t)G * Nn;
  float* qkv = (float*)p;
  float* outp = qkv + MgMax * LDQ;
  float* at = outp + MgMax * Cc;
  float* paccv = at + (size_t)G * Aa * Cc;
  float* paccs = paccv + (size_t)G * Hh * NCH * Aa * 64;
  float* av = paccs + (size_t)G * Hh * NCH * Aa;
  short* Apk = (short*)(av + (size_t)G * Hh * Aa * HD);   // aliased as Opk

  dim3 blk(256);
  // 0) pack weights (once per launch; deterministic)
  pack_w<<<dim3((96 * LDQ + 255) / 256), blk, 0, stream>>>(Wqkv, WQpk, LDQ);
  pack_w<<<dim3((96 * Cc + 255) / 256), blk, 0, stream>>>(Wproj, WPpk, Cc);

  for (int b0 = 0; b0 < Bb; b0 += G) {
    const int Gi = (b0 + G <= Bb) ? G : (Bb - b0);
    const int Mg = Gi * Nn;
    const int Mtiles = (Mg + 127) / 128;
    const float* xg = x + (size_t)b0 * Nn * Cc;
    float* outg = out + (size_t)b0 * Nn * Cc;

    // 1) pack x -> Apk, then qkv = x @ Wqkv (packed MFMA GEMM)
    pack_act<<<dim3((Mg * 96 + 255) / 256), blk, 0, stream>>>(xg, Apk, Mg);
    {
      const int nch = LDQ / 128;            // 18
      const int nwg = Mtiles * nch;
      gemm_pk2<<<dim3(nwg), blk, 0, stream>>>(Apk, WQpk, qkv, nullptr, Mg,
                                              LDQ, nch, nwg);
    }
    // 2) agent tokens (adaptive pool of q)
    pool_agents<<<dim3(Gi * Aa), blk, 0, stream>>>(qkv, at);
    // 3) agent attention partials + merge -> agent_v
    agent_attn_partial<<<dim3(NCH, Hh, Gi), blk, 0, stream>>>(qkv, at, paccv,
                                                              paccs);
    merge_agent<<<dim3(Gi * Hh), blk, 0, stream>>>(paccv, paccs, av);
    // 4) q attention -> outp
    q_attn_kernel<<<dim3((Nn + 255) / 256, Hh, Gi), blk, 0, stream>>>(
        qkv, at, av, outp);
    // 5) fused depthwise conv + split-pack -> Opk(=Apk)
    dwc_pack<<<dim3((Mg * 96 + 255) / 256), blk, 0, stream>>>(
        outp, qkv, dwcw, dwcb, Apk, Mg);
    // 6) final projection -> out_g (+bias)
    {
      const int nch = Cc / 128;             // 6
      const int nwg = Mtiles * nch;
      gemm_pk2<<<dim3(nwg), blk, 0, stream>>>(Apk, WPpk, outg, bproj, Mg,
                                              Cc, nch, nwg);
    }
  }
}

// Round 8
// 1055.302 us; speedup vs baseline: 2.9359x; 1.5357x over previous
//
#include <hip/hip_runtime.h>

namespace {

constexpr int Bb = 8;
constexpr int Nn = 4097;
constexpr int Cc = 768;
constexpr int Hh = 12;
constexpr int HD = 64;
constexpr int Aa = 49;
constexpr int LDQ = 3 * Cc;        // 2304 (qkv row stride)
constexpr int NCH = 8;             // j-chunks for agent attention
constexpr int CHUNK = (Nn + NCH - 1) / NCH;  // 513
constexpr float SCALE = 0.125f;    // hd^-0.5
constexpr int KP = 1536;           // packed plane row length (hi 768 | lo 768)

typedef short s16x8 __attribute__((ext_vector_type(8)));
typedef float f32x4 __attribute__((ext_vector_type(4)));

struct HL { short h, l; };

// Split fp32 into hi (truncated bf16, exact bits) + lo (RNE bf16 of residual).
__device__ inline HL splitbf(float v) {
  unsigned u = __float_as_uint(v);
  HL r;
  r.h = (short)(u >> 16);
  float hf = __uint_as_float(u & 0xffff0000u);
  float lf = v - hf;
  unsigned ul = __float_as_uint(lf);
  r.l = (short)((ul + 0x7fffu + ((ul >> 16) & 1u)) >> 16);
  return r;
}

// async global->LDS, 16B per lane (linear dest)
__device__ inline void gload16(const short* g, void* l) {
  __builtin_amdgcn_global_load_lds(
      (const __attribute__((address_space(1))) void*)g,
      (__attribute__((address_space(3))) void*)l, 16, 0, 0);
}

// ---------------------------------------------------------------------------
// Pack activations: src[M][768] fp32 -> dst[M][1536] bf16 = [hi | lo], with
// 16B-chunk XOR swizzle within each 64-elem window: chunk' = chunk ^ (m&7).
// ---------------------------------------------------------------------------
__global__ __launch_bounds__(256) void pack_act(
    const float* __restrict__ src, short* __restrict__ dst, int M) {
  int idx = blockIdx.x * 256 + threadIdx.x;
  if (idx >= M * 96) return;
  int m = idx / 96, kc = idx - m * 96;
  const float* s = src + (size_t)m * 768 + kc * 8;
  float4 v0 = *(const float4*)s;
  float4 v1 = *(const float4*)(s + 4);
  s16x8 hv, lv;
  HL r;
  r = splitbf(v0.x); hv[0] = r.h; lv[0] = r.l;
  r = splitbf(v0.y); hv[1] = r.h; lv[1] = r.l;
  r = splitbf(v0.z); hv[2] = r.h; lv[2] = r.l;
  r = splitbf(v0.w); hv[3] = r.h; lv[3] = r.l;
  r = splitbf(v1.x); hv[4] = r.h; lv[4] = r.l;
  r = splitbf(v1.y); hv[5] = r.h; lv[5] = r.l;
  r = splitbf(v1.z); hv[6] = r.h; lv[6] = r.l;
  r = splitbf(v1.w); hv[7] = r.h; lv[7] = r.l;
  int win = (kc >> 3) * 64;
  int jj = ((kc & 7) ^ (m & 7)) * 8;
  short* d = dst + (size_t)m * KP;
  *(s16x8*)&d[win + jj] = hv;
  *(s16x8*)&d[768 + win + jj] = lv;
}

// ---------------------------------------------------------------------------
// Pack weights: W[768][N] fp32 -> Wpk[N][1536] bf16 = [hi | lo], same swizzle
// keyed by (n&7).
// ---------------------------------------------------------------------------
__global__ __launch_bounds__(256) void pack_w(
    const float* __restrict__ W, short* __restrict__ Wpk, int N) {
  int idx = blockIdx.x * 256 + threadIdx.x;
  if (idx >= 96 * N) return;
  int kc = idx / N, n = idx - kc * N;
  s16x8 hv, lv;
#pragma unroll
  for (int i = 0; i < 8; ++i) {
    HL r = splitbf(W[(size_t)(kc * 8 + i) * N + n]);
    hv[i] = r.h; lv[i] = r.l;
  }
  int win = (kc >> 3) * 64;
  int jj = ((kc & 7) ^ (n & 7)) * 8;
  short* d = Wpk + (size_t)n * KP;
  *(s16x8*)&d[win + jj] = hv;
  *(s16x8*)&d[768 + win + jj] = lv;
}

// ---------------------------------------------------------------------------
// C[M x N] = A @ B (+bias) on packed planes. Per 64-K-chunk stage all four
// planes (64KB LDS), 96 mfma per barrier pair, 12 kt iterations.
// 1D grid with bijective XCD swizzle; n-fastest logical order.
// ---------------------------------------------------------------------------
__global__ __launch_bounds__(256) void gemm_pk2(
    const short* __restrict__ Apk, const short* __restrict__ Bpk,
    float* __restrict__ Cm, const float* __restrict__ bias,
    int Mr, int ldc, int nch, int nwg) {
  __shared__ __align__(16) short AsH[128 * 64], AsL[128 * 64];
  __shared__ __align__(16) short BsH[128 * 64], BsL[128 * 64];
  const int t = threadIdx.x;
  const int lane = t & 63;
  const int w = t >> 6;
  const int wr = w >> 1, wc = w & 1;
  const int l15 = lane & 15, l4 = lane >> 4;

  const int j = blockIdx.x;
  const int q = nwg >> 3, r = nwg & 7;
  const int xcd = j & 7, pos = j >> 3;
  const int logical =
      (xcd < r ? xcd * (q + 1) : r * (q + 1) + (xcd - r) * q) + pos;
  const int mt = logical / nch, nc = logical - mt * nch;
  const int m0 = mt * 128, n0 = nc * 128;

  f32x4 acc[4][4];
#pragma unroll
  for (int mi = 0; mi < 4; ++mi)
#pragma unroll
    for (int ni = 0; ni < 4; ++ni) acc[mi][ni] = (f32x4){0.f, 0.f, 0.f, 0.f};

  for (int kt = 0; kt < 12; ++kt) {
    const short* Ab = Apk + (size_t)m0 * KP + kt * 64;
    const short* Bt = Bpk + (size_t)n0 * KP + kt * 64;
    __syncthreads();
#pragma unroll
    for (int i = 0; i < 4; ++i) {
      const int o = (i * 256 + t) * 16;   // byte offset in 16KB plane
      const int row = o >> 7;
      const int ce = (o & 127) >> 1;      // element col (physical)
      gload16(Ab + (size_t)row * KP + ce, (char*)AsH + o);
      gload16(Ab + (size_t)row * KP + 768 + ce, (char*)AsL + o);
      gload16(Bt + (size_t)row * KP + ce, (char*)BsH + o);
      gload16(Bt + (size_t)row * KP + 768 + ce, (char*)BsL + o);
    }
    __syncthreads();
#pragma unroll
    for (int ks = 0; ks < 2; ++ks) {
      s16x8 ah[4], al[4], bh[4], bl[4];
#pragma unroll
      for (int mi = 0; mi < 4; ++mi) {
        int rr = wr * 64 + mi * 16 + l15;
        int off = rr * 64 + ((((ks << 2) + l4) ^ (l15 & 7)) << 3);
        ah[mi] = *(const s16x8*)&AsH[off];
        al[mi] = *(const s16x8*)&AsL[off];
      }
#pragma unroll
      for (int ni = 0; ni < 4; ++ni) {
        int rr = wc * 64 + ni * 16 + l15;
        int off = rr * 64 + ((((ks << 2) + l4) ^ (l15 & 7)) << 3);
        bh[ni] = *(const s16x8*)&BsH[off];
        bl[ni] = *(const s16x8*)&BsL[off];
      }
#pragma unroll
      for (int mi = 0; mi < 4; ++mi)
#pragma unroll
        for (int ni = 0; ni < 4; ++ni) {
          acc[mi][ni] = __builtin_amdgcn_mfma_f32_16x16x32_bf16(
              ah[mi], bh[ni], acc[mi][ni], 0, 0, 0);
          acc[mi][ni] = __builtin_amdgcn_mfma_f32_16x16x32_bf16(
              ah[mi], bl[ni], acc[mi][ni], 0, 0, 0);
          acc[mi][ni] = __builtin_amdgcn_mfma_f32_16x16x32_bf16(
              al[mi], bh[ni], acc[mi][ni], 0, 0, 0);
        }
    }
  }

#pragma unroll
  for (int mi = 0; mi < 4; ++mi) {
#pragma unroll
    for (int jr = 0; jr < 4; ++jr) {
      int gr = m0 + wr * 64 + mi * 16 + l4 * 4 + jr;
      if (gr < Mr) {
#pragma unroll
        for (int ni = 0; ni < 4; ++ni) {
          int gc = n0 + wc * 64 + ni * 16 + l15;
          float v = acc[mi][ni][jr];
          if (bias) v += bias[gc];
          Cm[(size_t)gr * ldc + gc] = v;
        }
      }
    }
  }
}

// ---------------------------------------------------------------------------
// Adaptive-pool agents: at[bg,a,c] = mean over q rows [s,e) of q[bg,l,c].
// ---------------------------------------------------------------------------
__global__ __launch_bounds__(256) void pool_agents(
    const float* __restrict__ qkv, float* __restrict__ at) {
  const int ba = blockIdx.x;
  const int bg = ba / Aa, a = ba % Aa;
  const int s = (a * 4096) / 49;
  const int e = ((a + 1) * 4096 + 48) / 49;
  const float w = 1.0f / (float)(e - s);
  const int t = threadIdx.x;
  for (int c = t; c < Cc; c += 256) {
    float sum = 0.f;
    for (int l = s; l < e; ++l)
      sum += qkv[(size_t)(bg * Nn + l) * LDQ + c];
    at[(size_t)(bg * Aa + a) * Cc + c] = sum * w;
  }
}

// ---------------------------------------------------------------------------
// Agent attention via MFMA split-bf16. Per (chunk,h,bg): 64(agents,pad) rows.
// Tiles of 64 j: S = ah @ K^T (MFMA), P = exp(S*scale) (masked), O += P @ V
// (MFMA, V^T + P transposed into XOR-swizzled LDS). Wave w owns agent rows
// [w*16,w*16+16) -> softmax row-sums stay within-wave.
// paccv/paccs = unnormalized partials per chunk (merged later).
// ---------------------------------------------------------------------------
__global__ __launch_bounds__(256) void agent_attn_mfma(
    const float* __restrict__ qkv, const float* __restrict__ at,
    float* __restrict__ paccv, float* __restrict__ paccs) {
  const int chunk = blockIdx.x, h = blockIdx.y, bg = blockIdx.z;
  __shared__ __align__(16) short AhH[4096], AhL[4096];  // ah [a][d]
  __shared__ __align__(16) short KH[4096], KL[4096];    // K  [j][d]
  __shared__ __align__(16) short VtH[4096], VtL[4096];  // V^T [c][j]
  __shared__ __align__(16) short PH[4096], PL[4096];    // P  [a][j]
  const int t = threadIdx.x;
  const int w = t >> 6, lane = t & 63, l15 = lane & 15, l4 = lane >> 4;

  // stage ah (rows >=49 zero), chunk-XOR (a&7)
  for (int idx = t; idx < 512; idx += 256) {
    int a = idx >> 3, c8 = idx & 7;
    float vals[8];
    if (a < Aa) {
      const float* src = &at[(size_t)(bg * Aa + a) * Cc + h * HD + c8 * 8];
      *(float4*)&vals[0] = *(const float4*)src;
      *(float4*)&vals[4] = *(const float4*)(src + 4);
    } else {
#pragma unroll
      for (int i = 0; i < 8; ++i) vals[i] = 0.f;
    }
    s16x8 hv, lv;
#pragma unroll
    for (int i = 0; i < 8; ++i) {
      HL r = splitbf(vals[i]);
      hv[i] = r.h; lv[i] = r.l;
    }
    int pos = a * 64 + ((c8 ^ (a & 7)) << 3);
    *(s16x8*)&AhH[pos] = hv;
    *(s16x8*)&AhL[pos] = lv;
  }

  f32x4 acc[4];
#pragma unroll
  for (int ni = 0; ni < 4; ++ni) acc[ni] = (f32x4){0.f, 0.f, 0.f, 0.f};
  float rs[4] = {0.f, 0.f, 0.f, 0.f};

  const int jstart = chunk * CHUNK;
  const int jend = min(jstart + CHUNK, Nn);
  const int srow = t >> 2, sc0 = (t & 3) * 16;  // staging coords

  for (int j0 = jstart; j0 < jend; j0 += 64) {
    __syncthreads();
    // ---- stage K (vectorized) and V^T (scalar transpose) ----
    {
      int jg = j0 + srow;
      float kv[16], vv[16];
      if (jg < jend) {
        const float* p = &qkv[(size_t)(bg * Nn + jg) * LDQ + Cc + h * HD + sc0];
#pragma unroll
        for (int r = 0; r < 4; ++r) {
          *(float4*)&kv[r * 4] = *(const float4*)(p + r * 4);
          *(float4*)&vv[r * 4] = *(const float4*)(p + Cc + r * 4);
        }
      } else {
#pragma unroll
        for (int i = 0; i < 16; ++i) { kv[i] = 0.f; vv[i] = 0.f; }
      }
#pragma unroll
      for (int r = 0; r < 2; ++r) {
        s16x8 hv, lv;
#pragma unroll
        for (int i = 0; i < 8; ++i) {
          HL s = splitbf(kv[r * 8 + i]);
          hv[i] = s.h; lv[i] = s.l;
        }
        int ch = (sc0 >> 3) + r;
        int pos = srow * 64 + ((ch ^ (srow & 7)) << 3);
        *(s16x8*)&KH[pos] = hv;
        *(s16x8*)&KL[pos] = lv;
      }
#pragma unroll
      for (int i = 0; i < 16; ++i) {
        HL s = splitbf(vv[i]);
        int c = sc0 + i;
        int pos = c * 64 + ((((srow >> 3) ^ (c & 7)) << 3)) + (srow & 7);
        VtH[pos] = s.h;
        VtL[pos] = s.l;
      }
    }
    __syncthreads();

    // ---- S = ah @ K^T ----
    f32x4 s[4];
#pragma unroll
    for (int ni = 0; ni < 4; ++ni) s[ni] = (f32x4){0.f, 0.f, 0.f, 0.f};
#pragma unroll
    for (int ks = 0; ks < 2; ++ks) {
      int sw = (((ks << 2) + l4) ^ (l15 & 7)) << 3;
      s16x8 ahh = *(const s16x8*)&AhH[(w * 16 + l15) * 64 + sw];
      s16x8 ahl = *(const s16x8*)&AhL[(w * 16 + l15) * 64 + sw];
#pragma unroll
      for (int ni = 0; ni < 4; ++ni) {
        s16x8 kh = *(const s16x8*)&KH[(ni * 16 + l15) * 64 + sw];
        s16x8 kl = *(const s16x8*)&KL[(ni * 16 + l15) * 64 + sw];
        s[ni] = __builtin_amdgcn_mfma_f32_16x16x32_bf16(ahh, kh, s[ni], 0, 0, 0);
        s[ni] = __builtin_amdgcn_mfma_f32_16x16x32_bf16(ahh, kl, s[ni], 0, 0, 0);
        s[ni] = __builtin_amdgcn_mfma_f32_16x16x32_bf16(ahl, kh, s[ni], 0, 0, 0);
      }
    }

    // ---- P = exp (masked), row-sum accumulate, transpose-write to LDS ----
#pragma unroll
    for (int ni = 0; ni < 4; ++ni) {
#pragma unroll
      for (int reg = 0; reg < 4; ++reg) {
        int jj = l15 + 16 * ni;
        float pv = (j0 + jj < jend) ? expf(s[ni][reg] * SCALE) : 0.f;
        rs[reg] += pv;
        HL r = splitbf(pv);
        int a = w * 16 + l4 * 4 + reg;
        int pos = a * 64 + ((((jj >> 3) ^ (a & 7)) << 3)) + (jj & 7);
        PH[pos] = r.h;
        PL[pos] = r.l;
      }
    }
    __syncthreads();

    // ---- O += P @ V ----
#pragma unroll
    for (int ks = 0; ks < 2; ++ks) {
      int sw = (((ks << 2) + l4) ^ (l15 & 7)) << 3;
      s16x8 ph = *(const s16x8*)&PH[(w * 16 + l15) * 64 + sw];
      s16x8 pl = *(const s16x8*)&PL[(w * 16 + l15) * 64 + sw];
#pragma unroll
      for (int ni = 0; ni < 4; ++ni) {
        s16x8 vh = *(const s16x8*)&VtH[(ni * 16 + l15) * 64 + sw];
        s16x8 vl = *(const s16x8*)&VtL[(ni * 16 + l15) * 64 + sw];
        acc[ni] = __builtin_amdgcn_mfma_f32_16x16x32_bf16(ph, vh, acc[ni], 0, 0, 0);
        acc[ni] = __builtin_amdgcn_mfma_f32_16x16x32_bf16(ph, vl, acc[ni], 0, 0, 0);
        acc[ni] = __builtin_amdgcn_mfma_f32_16x16x32_bf16(pl, vh, acc[ni], 0, 0, 0);
      }
    }
  }

  // ---- epilogue: reduce row-sums across the 16 j-lanes, write partials ----
#pragma unroll
  for (int reg = 0; reg < 4; ++reg) {
    rs[reg] += __shfl_xor(rs[reg], 1);
    rs[reg] += __shfl_xor(rs[reg], 2);
    rs[reg] += __shfl_xor(rs[reg], 4);
    rs[reg] += __shfl_xor(rs[reg], 8);
  }
  const int basev = ((bg * Hh + h) * NCH + chunk) * (Aa * 64);
#pragma unroll
  for (int reg = 0; reg < 4; ++reg) {
    int a = w * 16 + l4 * 4 + reg;
    if (a < Aa) {
#pragma unroll
      for (int ni = 0; ni < 4; ++ni)
        paccv[basev + a * 64 + l15 + 16 * ni] = acc[ni][reg];
      if (l15 == 0)
        paccs[((bg * Hh + h) * NCH + chunk) * Aa + a] = rs[reg];
    }
  }
}

// ---------------------------------------------------------------------------
// Merge chunk partials -> agent_v[bgh,a,c]
// ---------------------------------------------------------------------------
__global__ __launch_bounds__(256) void merge_agent(
    const float* __restrict__ paccv, const float* __restrict__ paccs,
    float* __restrict__ av) {
  const int bh = blockIdx.x;
  const int t = threadIdx.x;
  for (int idx = t; idx < Aa * HD; idx += 256) {
    int a = idx >> 6;
    float vs = 0.f, ss = 0.f;
#pragma unroll
    for (int ch = 0; ch < NCH; ++ch) {
      vs += paccv[(size_t)((bh * NCH + ch)) * (Aa * 64) + idx];
      ss += paccs[(bh * NCH + ch) * Aa + a];
    }
    av[(size_t)bh * (Aa * HD) + idx] = vs / ss;
  }
}

// ---------------------------------------------------------------------------
// q attention via MFMA split-bf16. Per (qtile,h,bg): 64 q rows. S = q @ ah^T,
// P = softmax over 49 agents (within-wave shfl row-sums), O = P @ agent_v
// (av^T + P transposed into XOR-swizzled LDS). Single-shot, 2 barriers.
// ---------------------------------------------------------------------------
__global__ __launch_bounds__(256) void q_attn_mfma(
    const float* __restrict__ qkv, const float* __restrict__ at,
    const float* __restrict__ av, float* __restrict__ outp) {
  const int i0 = blockIdx.x * 64, h = blockIdx.y, bg = blockIdx.z;
  __shared__ __align__(16) short AhH[4096], AhL[4096];   // ah [a][d]
  __shared__ __align__(16) short AvH[4096], AvL[4096];   // av^T [c][a]
  __shared__ __align__(16) short QH[4096], QL[4096];     // q [row][d]
  __shared__ __align__(16) short PH[4096], PL[4096];     // P [row][a]
  const int t = threadIdx.x;
  const int w = t >> 6, lane = t & 63, l15 = lane & 15, l4 = lane >> 4;

  // stage ah + av^T (rows/cols >=49 zero)
  for (int idx = t; idx < 512; idx += 256) {
    int a = idx >> 3, c8 = idx & 7;
    float vah[8], vav[8];
    if (a < Aa) {
      const float* s1 = &at[(size_t)(bg * Aa + a) * Cc + h * HD + c8 * 8];
      const float* s2 = &av[(size_t)(bg * Hh + h) * (Aa * HD) + a * HD + c8 * 8];
      *(float4*)&vah[0] = *(const float4*)s1;
      *(float4*)&vah[4] = *(const float4*)(s1 + 4);
      *(float4*)&vav[0] = *(const float4*)s2;
      *(float4*)&vav[4] = *(const float4*)(s2 + 4);
    } else {
#pragma unroll
      for (int i = 0; i < 8; ++i) { vah[i] = 0.f; vav[i] = 0.f; }
    }
    s16x8 hv, lv;
#pragma unroll
    for (int i = 0; i < 8; ++i) {
      HL r = splitbf(vah[i]);
      hv[i] = r.h; lv[i] = r.l;
    }
    int pos = a * 64 + ((c8 ^ (a & 7)) << 3);
    *(s16x8*)&AhH[pos] = hv;
    *(s16x8*)&AhL[pos] = lv;
    // av transposed: [c][a], chunk-XOR (c&7)
#pragma unroll
    for (int i = 0; i < 8; ++i) {
      HL r = splitbf(vav[i]);
      int c = c8 * 8 + i;
      int pos2 = c * 64 + ((((a >> 3) ^ (c & 7)) << 3)) + (a & 7);
      AvH[pos2] = r.h;
      AvL[pos2] = r.l;
    }
  }
  // stage q tile (rows beyond Nn zero)
  {
    int row = t >> 2, c0 = (t & 3) * 16;
    int ig = i0 + row;
    float qv[16];
    if (ig < Nn) {
      const float* p = &qkv[(size_t)(bg * Nn + ig) * LDQ + h * HD + c0];
#pragma unroll
      for (int r = 0; r < 4; ++r) *(float4*)&qv[r * 4] = *(const float4*)(p + r * 4);
    } else {
#pragma unroll
      for (int i = 0; i < 16; ++i) qv[i] = 0.f;
    }
#pragma unroll
    for (int r = 0; r < 2; ++r) {
      s16x8 hv, lv;
#pragma unroll
      for (int i = 0; i < 8; ++i) {
        HL s = splitbf(qv[r * 8 + i]);
        hv[i] = s.h; lv[i] = s.l;
      }
      int ch = (c0 >> 3) + r;
      int pos = row * 64 + ((ch ^ (row & 7)) << 3);
      *(s16x8*)&QH[pos] = hv;
      *(s16x8*)&QL[pos] = lv;
    }
  }
  __syncthreads();

  // ---- S = q @ ah^T ----
  f32x4 s[4];
#pragma unroll
  for (int ni = 0; ni < 4; ++ni) s[ni] = (f32x4){0.f, 0.f, 0.f, 0.f};
#pragma unroll
  for (int ks = 0; ks < 2; ++ks) {
    int sw = (((ks << 2) + l4) ^ (l15 & 7)) << 3;
    s16x8 qh = *(const s16x8*)&QH[(w * 16 + l15) * 64 + sw];
    s16x8 ql = *(const s16x8*)&QL[(w * 16 + l15) * 64 + sw];
#pragma unroll
    for (int ni = 0; ni < 4; ++ni) {
      s16x8 bh = *(const s16x8*)&AhH[(ni * 16 + l15) * 64 + sw];
      s16x8 bl = *(const s16x8*)&AhL[(ni * 16 + l15) * 64 + sw];
      s[ni] = __builtin_amdgcn_mfma_f32_16x16x32_bf16(qh, bh, s[ni], 0, 0, 0);
      s[ni] = __builtin_amdgcn_mfma_f32_16x16x32_bf16(qh, bl, s[ni], 0, 0, 0);
      s[ni] = __builtin_amdgcn_mfma_f32_16x16x32_bf16(ql, bh, s[ni], 0, 0, 0);
    }
  }

  // ---- softmax over agents (within-wave) + transpose-write P ----
  float rsum[4] = {0.f, 0.f, 0.f, 0.f};
#pragma unroll
  for (int ni = 0; ni < 4; ++ni) {
#pragma unroll
    for (int reg = 0; reg < 4; ++reg) {
      int a = l15 + 16 * ni;
      float pv = (a < Aa) ? expf(s[ni][reg] * SCALE) : 0.f;
      s[ni][reg] = pv;
      rsum[reg] += pv;
    }
  }
#pragma unroll
  for (int reg = 0; reg < 4; ++reg) {
    rsum[reg] += __shfl_xor(rsum[reg], 1);
    rsum[reg] += __shfl_xor(rsum[reg], 2);
    rsum[reg] += __shfl_xor(rsum[reg], 4);
    rsum[reg] += __shfl_xor(rsum[reg], 8);
    rsum[reg] = 1.0f / rsum[reg];
  }
#pragma unroll
  for (int ni = 0; ni < 4; ++ni) {
#pragma unroll
    for (int reg = 0; reg < 4; ++reg) {
      HL r = splitbf(s[ni][reg] * rsum[reg]);
      int row = w * 16 + l4 * 4 + reg;
      int a = l15 + 16 * ni;
      int pos = row * 64 + ((((a >> 3) ^ (row & 7)) << 3)) + (a & 7);
      PH[pos] = r.h;
      PL[pos] = r.l;
    }
  }
  __syncthreads();

  // ---- O = P @ agent_v ----
  f32x4 o[4];
#pragma unroll
  for (int ni = 0; ni < 4; ++ni) o[ni] = (f32x4){0.f, 0.f, 0.f, 0.f};
#pragma unroll
  for (int ks = 0; ks < 2; ++ks) {
    int sw = (((ks << 2) + l4) ^ (l15 & 7)) << 3;
    s16x8 ph = *(const s16x8*)&PH[(w * 16 + l15) * 64 + sw];
    s16x8 pl = *(const s16x8*)&PL[(w * 16 + l15) * 64 + sw];
#pragma unroll
    for (int ni = 0; ni < 4; ++ni) {
      s16x8 vh = *(const s16x8*)&AvH[(ni * 16 + l15) * 64 + sw];
      s16x8 vl = *(const s16x8*)&AvL[(ni * 16 + l15) * 64 + sw];
      o[ni] = __builtin_amdgcn_mfma_f32_16x16x32_bf16(ph, vh, o[ni], 0, 0, 0);
      o[ni] = __builtin_amdgcn_mfma_f32_16x16x32_bf16(ph, vl, o[ni], 0, 0, 0);
      o[ni] = __builtin_amdgcn_mfma_f32_16x16x32_bf16(pl, vh, o[ni], 0, 0, 0);
    }
  }

#pragma unroll
  for (int reg = 0; reg < 4; ++reg) {
    int ig = i0 + w * 16 + l4 * 4 + reg;
    if (ig < Nn) {
#pragma unroll
      for (int ni = 0; ni < 4; ++ni)
        outp[(size_t)(bg * Nn + ig) * Cc + h * HD + l15 + 16 * ni] = o[ni][reg];
    }
  }
}

// ---------------------------------------------------------------------------
// Fused: dwc(v) added to outp rows (<4096), then split+pack to Opk planes.
// ---------------------------------------------------------------------------
__global__ __launch_bounds__(256) void dwc_pack(
    const float* __restrict__ outp, const float* __restrict__ qkv,
    const float* __restrict__ w, const float* __restrict__ wb,
    short* __restrict__ Opk, int Mg) {
  int idx = blockIdx.x * 256 + threadIdx.x;
  if (idx >= Mg * 96) return;
  int m = idx / 96, kc = idx - m * 96;
  int bg = m / Nn, i = m - bg * Nn;
  const float* s = outp + (size_t)m * 768 + kc * 8;
  float val[8];
  float4 o0 = *(const float4*)s;
  float4 o1 = *(const float4*)(s + 4);
  val[0] = o0.x; val[1] = o0.y; val[2] = o0.z; val[3] = o0.w;
  val[4] = o1.x; val[5] = o1.y; val[6] = o1.z; val[7] = o1.w;

  if (i < Nn - 1) {
    const int c0 = kc * 8;
    const float* vb = &qkv[((size_t)bg * Nn + i) * LDQ + 2 * Cc + c0];
    const float4 z = make_float4(0.f, 0.f, 0.f, 0.f);
    float4 vm0 = (i > 0) ? *(const float4*)(vb - LDQ) : z;
    float4 vm1 = (i > 0) ? *(const float4*)(vb - LDQ + 4) : z;
    float4 v00 = *(const float4*)vb;
    float4 v01 = *(const float4*)(vb + 4);
    float4 vp0 = (i < 4095) ? *(const float4*)(vb + LDQ) : z;
    float4 vp1 = (i < 4095) ? *(const float4*)(vb + LDQ + 4) : z;
    float vm[8] = {vm0.x, vm0.y, vm0.z, vm0.w, vm1.x, vm1.y, vm1.z, vm1.w};
    float v0[8] = {v00.x, v00.y, v00.z, v00.w, v01.x, v01.y, v01.z, v01.w};
    float vp[8] = {vp0.x, vp0.y, vp0.z, vp0.w, vp1.x, vp1.y, vp1.z, vp1.w};
#pragma unroll
    for (int c = 0; c < 8; ++c) {
      val[c] += w[(c0 + c) * 3] * vm[c] + w[(c0 + c) * 3 + 1] * v0[c] +
                w[(c0 + c) * 3 + 2] * vp[c] + wb[c0 + c];
    }
  }

  s16x8 hv, lv;
#pragma unroll
  for (int c = 0; c < 8; ++c) {
    HL r = splitbf(val[c]);
    hv[c] = r.h; lv[c] = r.l;
  }
  int win = (kc >> 3) * 64;
  int jj = ((kc & 7) ^ (m & 7)) * 8;
  short* d = Opk + (size_t)m * KP;
  *(s16x8*)&d[win + jj] = hv;
  *(s16x8*)&d[768 + win + jj] = lv;
}

}  // namespace

extern "C" void kernel_launch(void* const* d_in, const int* in_sizes, int n_in,
                              void* d_out, int out_size, void* d_ws,
                              size_t ws_size, hipStream_t stream) {
  const float* x = (const float*)d_in[0];
  const float* Wqkv = (const float*)d_in[1];
  const float* Wproj = (const float*)d_in[2];
  const float* bproj = (const float*)d_in[3];
  const float* dwcw = (const float*)d_in[4];
  const float* dwcb = (const float*)d_in[5];
  float* out = (float*)d_out;

  // --- fixed workspace: packed weight planes ---
  char* p = (char*)d_ws;
  short* WQpk = (short*)p; p += (size_t)LDQ * KP * 2;   // 7,077,888 B
  short* WPpk = (short*)p; p += (size_t)Cc * KP * 2;    // 2,359,296 B
  const size_t fixedBytes = (size_t)p - (size_t)d_ws;

  // --- choose group size G (largest that fits) ---
  auto bytesFor = [&](int G) -> size_t {
    size_t Mg = (size_t)G * Nn;
    size_t Mpad = ((Mg + 127) / 128) * 128;
    size_t fl = Mg * LDQ + Mg * Cc +                       // qkv + outp
                (size_t)G * (Aa * Cc + Hh * NCH * Aa * 64 + Hh * NCH * Aa +
                             Hh * Aa * HD);
    return fixedBytes + fl * 4 + Mpad * KP * 2;            // + Apk/Opk
  };
  int G = 1;
  for (int g = Bb; g >= 1; --g) {
    if (bytesFor(g) <= ws_size) { G = g; break; }
  }

  const size_t MgMax = (size_t)G * Nn;
  float* qkv = (float*)p;
  float* outp = qkv + MgMax * LDQ;
  float* at = outp + MgMax * Cc;
  float* paccv = at + (size_t)G * Aa * Cc;
  float* paccs = paccv + (size_t)G * Hh * NCH * Aa * 64;
  float* av = paccs + (size_t)G * Hh * NCH * Aa;
  short* Apk = (short*)(av + (size_t)G * Hh * Aa * HD);   // aliased as Opk

  dim3 blk(256);
  // 0) pack weights (once per launch; deterministic)
  pack_w<<<dim3((96 * LDQ + 255) / 256), blk, 0, stream>>>(Wqkv, WQpk, LDQ);
  pack_w<<<dim3((96 * Cc + 255) / 256), blk, 0, stream>>>(Wproj, WPpk, Cc);

  for (int b0 = 0; b0 < Bb; b0 += G) {
    const int Gi = (b0 + G <= Bb) ? G : (Bb - b0);
    const int Mg = Gi * Nn;
    const int Mtiles = (Mg + 127) / 128;
    const float* xg = x + (size_t)b0 * Nn * Cc;
    float* outg = out + (size_t)b0 * Nn * Cc;

    // 1) pack x -> Apk, then qkv = x @ Wqkv (packed MFMA GEMM)
    pack_act<<<dim3((Mg * 96 + 255) / 256), blk, 0, stream>>>(xg, Apk, Mg);
    {
      const int nch = LDQ / 128;            // 18
      const int nwg = Mtiles * nch;
      gemm_pk2<<<dim3(nwg), blk, 0, stream>>>(Apk, WQpk, qkv, nullptr, Mg,
                                              LDQ, nch, nwg);
    }
    // 2) agent tokens (adaptive pool of q)
    pool_agents<<<dim3(Gi * Aa), blk, 0, stream>>>(qkv, at);
    // 3) agent attention partials (MFMA) + merge -> agent_v
    agent_attn_mfma<<<dim3(NCH, Hh, Gi), blk, 0, stream>>>(qkv, at, paccv,
                                                           paccs);
    merge_agent<<<dim3(Gi * Hh), blk, 0, stream>>>(paccv, paccs, av);
    // 4) q attention (MFMA) -> outp
    q_attn_mfma<<<dim3((Nn + 63) / 64, Hh, Gi), blk, 0, stream>>>(qkv, at, av,
                                                                  outp);
    // 5) fused depthwise conv + split-pack -> Opk(=Apk)
    dwc_pack<<<dim3((Mg * 96 + 255) / 256), blk, 0, stream>>>(
        outp, qkv, dwcw, dwcb, Apk, Mg);
    // 6) final projection -> out_g (+bias)
    {
      const int nch = Cc / 128;             // 6
      const int nwg = Mtiles * nch;
      gemm_pk2<<<dim3(nwg), blk, 0, stream>>>(Apk, WPpk, outg, bproj, Mg,
                                              Cc, nch, nwg);
    }
  }
}

// Round 9
// 842.493 us; speedup vs baseline: 3.6775x; 1.2526x over previous
//
#include <hip/hip_runtime.h>

namespace {

constexpr int Bb = 8;
constexpr int Nn = 4097;
constexpr int Cc = 768;
constexpr int Hh = 12;
constexpr int HD = 64;
constexpr int Aa = 49;
constexpr int LDQ = 3 * Cc;        // 2304 (qkv row stride)
constexpr int NCH = 8;             // j-chunks for agent attention
constexpr int CHUNK = (Nn + NCH - 1) / NCH;  // 513
constexpr float SCALE = 0.125f;    // hd^-0.5
constexpr int KP = 1536;           // packed plane row length (hi 768 | lo 768)

typedef short s16x8 __attribute__((ext_vector_type(8)));
typedef float f32x4 __attribute__((ext_vector_type(4)));

struct HL { short h, l; };

// Split fp32 into hi (truncated bf16, exact bits) + lo (RNE bf16 of residual).
__device__ inline HL splitbf(float v) {
  unsigned u = __float_as_uint(v);
  HL r;
  r.h = (short)(u >> 16);
  float hf = __uint_as_float(u & 0xffff0000u);
  float lf = v - hf;
  unsigned ul = __float_as_uint(lf);
  r.l = (short)((ul + 0x7fffu + ((ul >> 16) & 1u)) >> 16);
  return r;
}

// async global->LDS, 16B per lane (linear dest)
__device__ inline void gload16(const short* g, void* l) {
  __builtin_amdgcn_global_load_lds(
      (const __attribute__((address_space(1))) void*)g,
      (__attribute__((address_space(3))) void*)l, 16, 0, 0);
}

// ---------------------------------------------------------------------------
// Pack activations: src[M][768] fp32 -> dst[M][1536] bf16 = [hi | lo], with
// 16B-chunk XOR swizzle within each 64-elem window: chunk' = chunk ^ (m&7).
// ---------------------------------------------------------------------------
__global__ __launch_bounds__(256) void pack_act(
    const float* __restrict__ src, short* __restrict__ dst, int M) {
  int idx = blockIdx.x * 256 + threadIdx.x;
  if (idx >= M * 96) return;
  int m = idx / 96, kc = idx - m * 96;
  const float* s = src + (size_t)m * 768 + kc * 8;
  float4 v0 = *(const float4*)s;
  float4 v1 = *(const float4*)(s + 4);
  s16x8 hv, lv;
  HL r;
  r = splitbf(v0.x); hv[0] = r.h; lv[0] = r.l;
  r = splitbf(v0.y); hv[1] = r.h; lv[1] = r.l;
  r = splitbf(v0.z); hv[2] = r.h; lv[2] = r.l;
  r = splitbf(v0.w); hv[3] = r.h; lv[3] = r.l;
  r = splitbf(v1.x); hv[4] = r.h; lv[4] = r.l;
  r = splitbf(v1.y); hv[5] = r.h; lv[5] = r.l;
  r = splitbf(v1.z); hv[6] = r.h; lv[6] = r.l;
  r = splitbf(v1.w); hv[7] = r.h; lv[7] = r.l;
  int win = (kc >> 3) * 64;
  int jj = ((kc & 7) ^ (m & 7)) * 8;
  short* d = dst + (size_t)m * KP;
  *(s16x8*)&d[win + jj] = hv;
  *(s16x8*)&d[768 + win + jj] = lv;
}

// ---------------------------------------------------------------------------
// Pack weights: W[768][N] fp32 -> Wpk[N][1536] bf16 = [hi | lo], same swizzle
// keyed by (n&7).
// ---------------------------------------------------------------------------
__global__ __launch_bounds__(256) void pack_w(
    const float* __restrict__ W, short* __restrict__ Wpk, int N) {
  int idx = blockIdx.x * 256 + threadIdx.x;
  if (idx >= 96 * N) return;
  int kc = idx / N, n = idx - kc * N;
  s16x8 hv, lv;
#pragma unroll
  for (int i = 0; i < 8; ++i) {
    HL r = splitbf(W[(size_t)(kc * 8 + i) * N + n]);
    hv[i] = r.h; lv[i] = r.l;
  }
  int win = (kc >> 3) * 64;
  int jj = ((kc & 7) ^ (n & 7)) * 8;
  short* d = Wpk + (size_t)n * KP;
  *(s16x8*)&d[win + jj] = hv;
  *(s16x8*)&d[768 + win + jj] = lv;
}

// ---------------------------------------------------------------------------
// C[M x N] = A @ B (+bias) on packed planes. Per 64-K-chunk stage all four
// planes (64KB LDS), 96 mfma per barrier pair, 12 kt iterations.
// 1D grid with bijective XCD swizzle; n-fastest logical order.
// ---------------------------------------------------------------------------
__global__ __launch_bounds__(256) void gemm_pk2(
    const short* __restrict__ Apk, const short* __restrict__ Bpk,
    float* __restrict__ Cm, const float* __restrict__ bias,
    int Mr, int ldc, int nch, int nwg) {
  __shared__ __align__(16) short AsH[128 * 64], AsL[128 * 64];
  __shared__ __align__(16) short BsH[128 * 64], BsL[128 * 64];
  const int t = threadIdx.x;
  const int lane = t & 63;
  const int w = t >> 6;
  const int wr = w >> 1, wc = w & 1;
  const int l15 = lane & 15, l4 = lane >> 4;

  const int j = blockIdx.x;
  const int q = nwg >> 3, r = nwg & 7;
  const int xcd = j & 7, pos = j >> 3;
  const int logical =
      (xcd < r ? xcd * (q + 1) : r * (q + 1) + (xcd - r) * q) + pos;
  const int mt = logical / nch, nc = logical - mt * nch;
  const int m0 = mt * 128, n0 = nc * 128;

  f32x4 acc[4][4];
#pragma unroll
  for (int mi = 0; mi < 4; ++mi)
#pragma unroll
    for (int ni = 0; ni < 4; ++ni) acc[mi][ni] = (f32x4){0.f, 0.f, 0.f, 0.f};

  for (int kt = 0; kt < 12; ++kt) {
    const short* Ab = Apk + (size_t)m0 * KP + kt * 64;
    const short* Bt = Bpk + (size_t)n0 * KP + kt * 64;
    __syncthreads();
#pragma unroll
    for (int i = 0; i < 4; ++i) {
      const int o = (i * 256 + t) * 16;   // byte offset in 16KB plane
      const int row = o >> 7;
      const int ce = (o & 127) >> 1;      // element col (physical)
      gload16(Ab + (size_t)row * KP + ce, (char*)AsH + o);
      gload16(Ab + (size_t)row * KP + 768 + ce, (char*)AsL + o);
      gload16(Bt + (size_t)row * KP + ce, (char*)BsH + o);
      gload16(Bt + (size_t)row * KP + 768 + ce, (char*)BsL + o);
    }
    __syncthreads();
#pragma unroll
    for (int ks = 0; ks < 2; ++ks) {
      s16x8 ah[4], al[4], bh[4], bl[4];
#pragma unroll
      for (int mi = 0; mi < 4; ++mi) {
        int rr = wr * 64 + mi * 16 + l15;
        int off = rr * 64 + ((((ks << 2) + l4) ^ (l15 & 7)) << 3);
        ah[mi] = *(const s16x8*)&AsH[off];
        al[mi] = *(const s16x8*)&AsL[off];
      }
#pragma unroll
      for (int ni = 0; ni < 4; ++ni) {
        int rr = wc * 64 + ni * 16 + l15;
        int off = rr * 64 + ((((ks << 2) + l4) ^ (l15 & 7)) << 3);
        bh[ni] = *(const s16x8*)&BsH[off];
        bl[ni] = *(const s16x8*)&BsL[off];
      }
#pragma unroll
      for (int mi = 0; mi < 4; ++mi)
#pragma unroll
        for (int ni = 0; ni < 4; ++ni) {
          acc[mi][ni] = __builtin_amdgcn_mfma_f32_16x16x32_bf16(
              ah[mi], bh[ni], acc[mi][ni], 0, 0, 0);
          acc[mi][ni] = __builtin_amdgcn_mfma_f32_16x16x32_bf16(
              ah[mi], bl[ni], acc[mi][ni], 0, 0, 0);
          acc[mi][ni] = __builtin_amdgcn_mfma_f32_16x16x32_bf16(
              al[mi], bh[ni], acc[mi][ni], 0, 0, 0);
        }
    }
  }

#pragma unroll
  for (int mi = 0; mi < 4; ++mi) {
#pragma unroll
    for (int jr = 0; jr < 4; ++jr) {
      int gr = m0 + wr * 64 + mi * 16 + l4 * 4 + jr;
      if (gr < Mr) {
#pragma unroll
        for (int ni = 0; ni < 4; ++ni) {
          int gc = n0 + wc * 64 + ni * 16 + l15;
          float v = acc[mi][ni][jr];
          if (bias) v += bias[gc];
          Cm[(size_t)gr * ldc + gc] = v;
        }
      }
    }
  }
}

// ---------------------------------------------------------------------------
// Adaptive-pool agents: at[bg,a,c] = mean over q rows [s,e) of q[bg,l,c].
// float4 over c (threads 0..191), serial loop over l.
// ---------------------------------------------------------------------------
__global__ __launch_bounds__(256) void pool_agents(
    const float* __restrict__ qkv, float* __restrict__ at) {
  const int ba = blockIdx.x;
  const int bg = ba / Aa, a = ba % Aa;
  const int s = (a * 4096) / 49;
  const int e = ((a + 1) * 4096 + 48) / 49;
  const float w = 1.0f / (float)(e - s);
  const int t = threadIdx.x;
  const int c4 = t * 4;
  if (c4 >= Cc) return;
  f32x4 sum = (f32x4){0.f, 0.f, 0.f, 0.f};
#pragma unroll 4
  for (int l = s; l < e; ++l) {
    const float4 v = *(const float4*)&qkv[(size_t)(bg * Nn + l) * LDQ + c4];
    sum[0] += v.x; sum[1] += v.y; sum[2] += v.z; sum[3] += v.w;
  }
  float4 o;
  o.x = sum[0] * w; o.y = sum[1] * w; o.z = sum[2] * w; o.w = sum[3] * w;
  *(float4*)&at[(size_t)(bg * Aa + a) * Cc + c4] = o;
}

// ---------------------------------------------------------------------------
// Agent attention via MFMA split-bf16. Per (chunk,h,bg): 64(agents,pad) rows.
// Tiles of 64 j: S = ah @ K^T (MFMA), P = exp(S*scale) (masked), O += P @ V.
// P planes ALIAS the K planes (written after S-MFMA barrier) -> 48KB LDS,
// 3 blocks/CU. Wave w owns agent rows [w*16,w*16+16).
// ---------------------------------------------------------------------------
__global__ __launch_bounds__(256) void agent_attn_mfma(
    const float* __restrict__ qkv, const float* __restrict__ at,
    float* __restrict__ paccv, float* __restrict__ paccs) {
  const int chunk = blockIdx.x, h = blockIdx.y, bg = blockIdx.z;
  __shared__ __align__(16) short AhH[4096], AhL[4096];  // ah [a][d]
  __shared__ __align__(16) short KH[4096], KL[4096];    // K [j][d]; P aliases
  __shared__ __align__(16) short VtH[4096], VtL[4096];  // V^T [c][j]
  const int t = threadIdx.x;
  const int w = t >> 6, lane = t & 63, l15 = lane & 15, l4 = lane >> 4;

  // stage ah (rows >=49 zero), chunk-XOR (a&7)
  for (int idx = t; idx < 512; idx += 256) {
    int a = idx >> 3, c8 = idx & 7;
    float vals[8];
    if (a < Aa) {
      const float* src = &at[(size_t)(bg * Aa + a) * Cc + h * HD + c8 * 8];
      *(float4*)&vals[0] = *(const float4*)src;
      *(float4*)&vals[4] = *(const float4*)(src + 4);
    } else {
#pragma unroll
      for (int i = 0; i < 8; ++i) vals[i] = 0.f;
    }
    s16x8 hv, lv;
#pragma unroll
    for (int i = 0; i < 8; ++i) {
      HL r = splitbf(vals[i]);
      hv[i] = r.h; lv[i] = r.l;
    }
    int pos = a * 64 + ((c8 ^ (a & 7)) << 3);
    *(s16x8*)&AhH[pos] = hv;
    *(s16x8*)&AhL[pos] = lv;
  }

  f32x4 acc[4];
#pragma unroll
  for (int ni = 0; ni < 4; ++ni) acc[ni] = (f32x4){0.f, 0.f, 0.f, 0.f};
  float rs[4] = {0.f, 0.f, 0.f, 0.f};

  const int jstart = chunk * CHUNK;
  const int jend = min(jstart + CHUNK, Nn);
  const int srow = t >> 2, sc0 = (t & 3) * 16;  // staging coords

  for (int j0 = jstart; j0 < jend; j0 += 64) {
    __syncthreads();  // prev PV done (P reads from K planes finished)
    // ---- stage K (vectorized) and V^T (scalar transpose) ----
    {
      int jg = j0 + srow;
      float kv[16], vv[16];
      if (jg < jend) {
        const float* p = &qkv[(size_t)(bg * Nn + jg) * LDQ + Cc + h * HD + sc0];
#pragma unroll
        for (int r = 0; r < 4; ++r) {
          *(float4*)&kv[r * 4] = *(const float4*)(p + r * 4);
          *(float4*)&vv[r * 4] = *(const float4*)(p + Cc + r * 4);
        }
      } else {
#pragma unroll
        for (int i = 0; i < 16; ++i) { kv[i] = 0.f; vv[i] = 0.f; }
      }
#pragma unroll
      for (int r = 0; r < 2; ++r) {
        s16x8 hv, lv;
#pragma unroll
        for (int i = 0; i < 8; ++i) {
          HL s = splitbf(kv[r * 8 + i]);
          hv[i] = s.h; lv[i] = s.l;
        }
        int ch = (sc0 >> 3) + r;
        int pos = srow * 64 + ((ch ^ (srow & 7)) << 3);
        *(s16x8*)&KH[pos] = hv;
        *(s16x8*)&KL[pos] = lv;
      }
#pragma unroll
      for (int i = 0; i < 16; ++i) {
        HL s = splitbf(vv[i]);
        int c = sc0 + i;
        int pos = c * 64 + ((((srow >> 3) ^ (c & 7)) << 3)) + (srow & 7);
        VtH[pos] = s.h;
        VtL[pos] = s.l;
      }
    }
    __syncthreads();

    // ---- S = ah @ K^T ----
    f32x4 s[4];
#pragma unroll
    for (int ni = 0; ni < 4; ++ni) s[ni] = (f32x4){0.f, 0.f, 0.f, 0.f};
#pragma unroll
    for (int ks = 0; ks < 2; ++ks) {
      int sw = (((ks << 2) + l4) ^ (l15 & 7)) << 3;
      s16x8 ahh = *(const s16x8*)&AhH[(w * 16 + l15) * 64 + sw];
      s16x8 ahl = *(const s16x8*)&AhL[(w * 16 + l15) * 64 + sw];
#pragma unroll
      for (int ni = 0; ni < 4; ++ni) {
        s16x8 kh = *(const s16x8*)&KH[(ni * 16 + l15) * 64 + sw];
        s16x8 kl = *(const s16x8*)&KL[(ni * 16 + l15) * 64 + sw];
        s[ni] = __builtin_amdgcn_mfma_f32_16x16x32_bf16(ahh, kh, s[ni], 0, 0, 0);
        s[ni] = __builtin_amdgcn_mfma_f32_16x16x32_bf16(ahh, kl, s[ni], 0, 0, 0);
        s[ni] = __builtin_amdgcn_mfma_f32_16x16x32_bf16(ahl, kh, s[ni], 0, 0, 0);
      }
    }
    __syncthreads();  // all waves done reading K -> P may overwrite

    // ---- P = exp (masked), row-sum accumulate, transpose-write into K planes
#pragma unroll
    for (int ni = 0; ni < 4; ++ni) {
#pragma unroll
      for (int reg = 0; reg < 4; ++reg) {
        int jj = l15 + 16 * ni;
        float pv = (j0 + jj < jend) ? expf(s[ni][reg] * SCALE) : 0.f;
        rs[reg] += pv;
        HL r = splitbf(pv);
        int a = w * 16 + l4 * 4 + reg;
        int pos = a * 64 + ((((jj >> 3) ^ (a & 7)) << 3)) + (jj & 7);
        KH[pos] = r.h;
        KL[pos] = r.l;
      }
    }
    __syncthreads();

    // ---- O += P @ V ----
#pragma unroll
    for (int ks = 0; ks < 2; ++ks) {
      int sw = (((ks << 2) + l4) ^ (l15 & 7)) << 3;
      s16x8 ph = *(const s16x8*)&KH[(w * 16 + l15) * 64 + sw];
      s16x8 pl = *(const s16x8*)&KL[(w * 16 + l15) * 64 + sw];
#pragma unroll
      for (int ni = 0; ni < 4; ++ni) {
        s16x8 vh = *(const s16x8*)&VtH[(ni * 16 + l15) * 64 + sw];
        s16x8 vl = *(const s16x8*)&VtL[(ni * 16 + l15) * 64 + sw];
        acc[ni] = __builtin_amdgcn_mfma_f32_16x16x32_bf16(ph, vh, acc[ni], 0, 0, 0);
        acc[ni] = __builtin_amdgcn_mfma_f32_16x16x32_bf16(ph, vl, acc[ni], 0, 0, 0);
        acc[ni] = __builtin_amdgcn_mfma_f32_16x16x32_bf16(pl, vh, acc[ni], 0, 0, 0);
      }
    }
  }

  // ---- epilogue: reduce row-sums across the 16 j-lanes, write partials ----
#pragma unroll
  for (int reg = 0; reg < 4; ++reg) {
    rs[reg] += __shfl_xor(rs[reg], 1);
    rs[reg] += __shfl_xor(rs[reg], 2);
    rs[reg] += __shfl_xor(rs[reg], 4);
    rs[reg] += __shfl_xor(rs[reg], 8);
  }
  const int basev = ((bg * Hh + h) * NCH + chunk) * (Aa * 64);
#pragma unroll
  for (int reg = 0; reg < 4; ++reg) {
    int a = w * 16 + l4 * 4 + reg;
    if (a < Aa) {
#pragma unroll
      for (int ni = 0; ni < 4; ++ni)
        paccv[basev + a * 64 + l15 + 16 * ni] = acc[ni][reg];
      if (l15 == 0)
        paccs[((bg * Hh + h) * NCH + chunk) * Aa + a] = rs[reg];
    }
  }
}

// ---------------------------------------------------------------------------
// Merge chunk partials -> agent_v[bgh,a,c]
// ---------------------------------------------------------------------------
__global__ __launch_bounds__(256) void merge_agent(
    const float* __restrict__ paccv, const float* __restrict__ paccs,
    float* __restrict__ av) {
  const int bh = blockIdx.x;
  const int t = threadIdx.x;
  for (int idx = t; idx < Aa * HD; idx += 256) {
    int a = idx >> 6;
    float vs = 0.f, ss = 0.f;
#pragma unroll
    for (int ch = 0; ch < NCH; ++ch) {
      vs += paccv[(size_t)((bh * NCH + ch)) * (Aa * 64) + idx];
      ss += paccs[(bh * NCH + ch) * Aa + a];
    }
    av[(size_t)bh * (Aa * HD) + idx] = vs / ss;
  }
}

// ---------------------------------------------------------------------------
// FUSED q attention + depthwise conv + split-pack. Per (qtile,h,bg): 64 q
// rows x this head's 64 channels. S = q @ ah^T, P = softmax (within-wave),
// O = P @ agent_v; then dwc(v) added in-register (rows < Nn-1) and the
// result split+packed directly into Opk (h-local windows). P aliases Q
// planes -> 48KB LDS. outp buffer is never materialized.
// ---------------------------------------------------------------------------
__global__ __launch_bounds__(256) void q_attn_dwc(
    const float* __restrict__ qkv, const float* __restrict__ at,
    const float* __restrict__ av, const float* __restrict__ dwcw,
    const float* __restrict__ dwcb, short* __restrict__ Opk) {
  const int i0 = blockIdx.x * 64, h = blockIdx.y, bg = blockIdx.z;
  __shared__ __align__(16) short AhH[4096], AhL[4096];   // ah [a][d]
  __shared__ __align__(16) short AvH[4096], AvL[4096];   // av^T [c][a]
  __shared__ __align__(16) short QH[4096], QL[4096];     // q [row][d]; P alias
  const int t = threadIdx.x;
  const int w = t >> 6, lane = t & 63, l15 = lane & 15, l4 = lane >> 4;

  // stage ah + av^T (rows/cols >=49 zero)
  for (int idx = t; idx < 512; idx += 256) {
    int a = idx >> 3, c8 = idx & 7;
    float vah[8], vav[8];
    if (a < Aa) {
      const float* s1 = &at[(size_t)(bg * Aa + a) * Cc + h * HD + c8 * 8];
      const float* s2 = &av[(size_t)(bg * Hh + h) * (Aa * HD) + a * HD + c8 * 8];
      *(float4*)&vah[0] = *(const float4*)s1;
      *(float4*)&vah[4] = *(const float4*)(s1 + 4);
      *(float4*)&vav[0] = *(const float4*)s2;
      *(float4*)&vav[4] = *(const float4*)(s2 + 4);
    } else {
#pragma unroll
      for (int i = 0; i < 8; ++i) { vah[i] = 0.f; vav[i] = 0.f; }
    }
    s16x8 hv, lv;
#pragma unroll
    for (int i = 0; i < 8; ++i) {
      HL r = splitbf(vah[i]);
      hv[i] = r.h; lv[i] = r.l;
    }
    int pos = a * 64 + ((c8 ^ (a & 7)) << 3);
    *(s16x8*)&AhH[pos] = hv;
    *(s16x8*)&AhL[pos] = lv;
#pragma unroll
    for (int i = 0; i < 8; ++i) {
      HL r = splitbf(vav[i]);
      int c = c8 * 8 + i;
      int pos2 = c * 64 + ((((a >> 3) ^ (c & 7)) << 3)) + (a & 7);
      AvH[pos2] = r.h;
      AvL[pos2] = r.l;
    }
  }
  // stage q tile (rows beyond Nn zero)
  {
    int row = t >> 2, c0 = (t & 3) * 16;
    int ig = i0 + row;
    float qv[16];
    if (ig < Nn) {
      const float* p = &qkv[(size_t)(bg * Nn + ig) * LDQ + h * HD + c0];
#pragma unroll
      for (int r = 0; r < 4; ++r) *(float4*)&qv[r * 4] = *(const float4*)(p + r * 4);
    } else {
#pragma unroll
      for (int i = 0; i < 16; ++i) qv[i] = 0.f;
    }
#pragma unroll
    for (int r = 0; r < 2; ++r) {
      s16x8 hv, lv;
#pragma unroll
      for (int i = 0; i < 8; ++i) {
        HL s = splitbf(qv[r * 8 + i]);
        hv[i] = s.h; lv[i] = s.l;
      }
      int ch = (c0 >> 3) + r;
      int pos = row * 64 + ((ch ^ (row & 7)) << 3);
      *(s16x8*)&QH[pos] = hv;
      *(s16x8*)&QL[pos] = lv;
    }
  }
  __syncthreads();

  // ---- S = q @ ah^T ----
  f32x4 s[4];
#pragma unroll
  for (int ni = 0; ni < 4; ++ni) s[ni] = (f32x4){0.f, 0.f, 0.f, 0.f};
#pragma unroll
  for (int ks = 0; ks < 2; ++ks) {
    int sw = (((ks << 2) + l4) ^ (l15 & 7)) << 3;
    s16x8 qh = *(const s16x8*)&QH[(w * 16 + l15) * 64 + sw];
    s16x8 ql = *(const s16x8*)&QL[(w * 16 + l15) * 64 + sw];
#pragma unroll
    for (int ni = 0; ni < 4; ++ni) {
      s16x8 bh = *(const s16x8*)&AhH[(ni * 16 + l15) * 64 + sw];
      s16x8 bl = *(const s16x8*)&AhL[(ni * 16 + l15) * 64 + sw];
      s[ni] = __builtin_amdgcn_mfma_f32_16x16x32_bf16(qh, bh, s[ni], 0, 0, 0);
      s[ni] = __builtin_amdgcn_mfma_f32_16x16x32_bf16(qh, bl, s[ni], 0, 0, 0);
      s[ni] = __builtin_amdgcn_mfma_f32_16x16x32_bf16(ql, bh, s[ni], 0, 0, 0);
    }
  }
  __syncthreads();  // all waves done reading Q -> P may overwrite

  // ---- softmax over agents (within-wave) + transpose-write P into Q planes
  float rsum[4] = {0.f, 0.f, 0.f, 0.f};
#pragma unroll
  for (int ni = 0; ni < 4; ++ni) {
#pragma unroll
    for (int reg = 0; reg < 4; ++reg) {
      int a = l15 + 16 * ni;
      float pv = (a < Aa) ? expf(s[ni][reg] * SCALE) : 0.f;
      s[ni][reg] = pv;
      rsum[reg] += pv;
    }
  }
#pragma unroll
  for (int reg = 0; reg < 4; ++reg) {
    rsum[reg] += __shfl_xor(rsum[reg], 1);
    rsum[reg] += __shfl_xor(rsum[reg], 2);
    rsum[reg] += __shfl_xor(rsum[reg], 4);
    rsum[reg] += __shfl_xor(rsum[reg], 8);
    rsum[reg] = 1.0f / rsum[reg];
  }
#pragma unroll
  for (int ni = 0; ni < 4; ++ni) {
#pragma unroll
    for (int reg = 0; reg < 4; ++reg) {
      HL r = splitbf(s[ni][reg] * rsum[reg]);
      int row = w * 16 + l4 * 4 + reg;
      int a = l15 + 16 * ni;
      int pos = row * 64 + ((((a >> 3) ^ (row & 7)) << 3)) + (a & 7);
      QH[pos] = r.h;
      QL[pos] = r.l;
    }
  }
  __syncthreads();

  // ---- O = P @ agent_v ----
  f32x4 o[4];
#pragma unroll
  for (int ni = 0; ni < 4; ++ni) o[ni] = (f32x4){0.f, 0.f, 0.f, 0.f};
#pragma unroll
  for (int ks = 0; ks < 2; ++ks) {
    int sw = (((ks << 2) + l4) ^ (l15 & 7)) << 3;
    s16x8 ph = *(const s16x8*)&QH[(w * 16 + l15) * 64 + sw];
    s16x8 pl = *(const s16x8*)&QL[(w * 16 + l15) * 64 + sw];
#pragma unroll
    for (int ni = 0; ni < 4; ++ni) {
      s16x8 vh = *(const s16x8*)&AvH[(ni * 16 + l15) * 64 + sw];
      s16x8 vl = *(const s16x8*)&AvL[(ni * 16 + l15) * 64 + sw];
      o[ni] = __builtin_amdgcn_mfma_f32_16x16x32_bf16(ph, vh, o[ni], 0, 0, 0);
      o[ni] = __builtin_amdgcn_mfma_f32_16x16x32_bf16(ph, vl, o[ni], 0, 0, 0);
      o[ni] = __builtin_amdgcn_mfma_f32_16x16x32_bf16(pl, vh, o[ni], 0, 0, 0);
    }
  }

  // ---- epilogue: + dwc(v) in-register, split, pack straight into Opk ----
#pragma unroll
  for (int reg = 0; reg < 4; ++reg) {
    int ig = i0 + w * 16 + l4 * 4 + reg;
    if (ig < Nn) {
      const size_t m = (size_t)bg * Nn + ig;
#pragma unroll
      for (int ni = 0; ni < 4; ++ni) {
        int c = h * HD + l15 + 16 * ni;   // global channel
        float val = o[ni][reg];
        if (ig < Nn - 1) {
          const float* vb = &qkv[m * LDQ + 2 * Cc + c];
          float vm = (ig > 0) ? vb[-LDQ] : 0.f;
          float v0 = vb[0];
          float vp = (ig < 4095) ? vb[LDQ] : 0.f;
          val += dwcw[c * 3] * vm + dwcw[c * 3 + 1] * v0 +
                 dwcw[c * 3 + 2] * vp + dwcb[c];
        }
        HL r = splitbf(val);
        int kc = c >> 3;
        int win = (kc >> 3) * 64;         // = h*64
        int jj = ((kc & 7) ^ ((int)m & 7)) * 8 + (c & 7);
        Opk[m * KP + win + jj] = r.h;
        Opk[m * KP + 768 + win + jj] = r.l;
      }
    }
  }
}

}  // namespace

extern "C" void kernel_launch(void* const* d_in, const int* in_sizes, int n_in,
                              void* d_out, int out_size, void* d_ws,
                              size_t ws_size, hipStream_t stream) {
  const float* x = (const float*)d_in[0];
  const float* Wqkv = (const float*)d_in[1];
  const float* Wproj = (const float*)d_in[2];
  const float* bproj = (const float*)d_in[3];
  const float* dwcw = (const float*)d_in[4];
  const float* dwcb = (const float*)d_in[5];
  float* out = (float*)d_out;

  // --- fixed workspace: packed weight planes ---
  char* p = (char*)d_ws;
  short* WQpk = (short*)p; p += (size_t)LDQ * KP * 2;   // 7,077,888 B
  short* WPpk = (short*)p; p += (size_t)Cc * KP * 2;    // 2,359,296 B
  const size_t fixedBytes = (size_t)p - (size_t)d_ws;

  // --- choose group size G (largest that fits; no outp buffer anymore) ---
  auto bytesFor = [&](int G) -> size_t {
    size_t Mg = (size_t)G * Nn;
    size_t Mpad = ((Mg + 127) / 128) * 128;
    size_t fl = Mg * LDQ +
                (size_t)G * (Aa * Cc + Hh * NCH * Aa * 64 + Hh * NCH * Aa +
                             Hh * Aa * HD);
    return fixedBytes + fl * 4 + Mpad * KP * 2;            // + Apk/Opk
  };
  int G = 1;
  for (int g = Bb; g >= 1; --g) {
    if (bytesFor(g) <= ws_size) { G = g; break; }
  }

  const size_t MgMax = (size_t)G * Nn;
  float* qkv = (float*)p;
  float* at = qkv + MgMax * LDQ;
  float* paccv = at + (size_t)G * Aa * Cc;
  float* paccs = paccv + (size_t)G * Hh * NCH * Aa * 64;
  float* av = paccs + (size_t)G * Hh * NCH * Aa;
  short* Apk = (short*)(av + (size_t)G * Hh * Aa * HD);   // aliased as Opk

  dim3 blk(256);
  // 0) pack weights (once per launch; deterministic)
  pack_w<<<dim3((96 * LDQ + 255) / 256), blk, 0, stream>>>(Wqkv, WQpk, LDQ);
  pack_w<<<dim3((96 * Cc + 255) / 256), blk, 0, stream>>>(Wproj, WPpk, Cc);

  for (int b0 = 0; b0 < Bb; b0 += G) {
    const int Gi = (b0 + G <= Bb) ? G : (Bb - b0);
    const int Mg = Gi * Nn;
    const int Mtiles = (Mg + 127) / 128;
    const float* xg = x + (size_t)b0 * Nn * Cc;
    float* outg = out + (size_t)b0 * Nn * Cc;

    // 1) pack x -> Apk, then qkv = x @ Wqkv (packed MFMA GEMM)
    pack_act<<<dim3((Mg * 96 + 255) / 256), blk, 0, stream>>>(xg, Apk, Mg);
    {
      const int nch = LDQ / 128;            // 18
      const int nwg = Mtiles * nch;
      gemm_pk2<<<dim3(nwg), blk, 0, stream>>>(Apk, WQpk, qkv, nullptr, Mg,
                                              LDQ, nch, nwg);
    }
    // 2) agent tokens (adaptive pool of q)
    pool_agents<<<dim3(Gi * Aa), blk, 0, stream>>>(qkv, at);
    // 3) agent attention partials (MFMA) + merge -> agent_v
    agent_attn_mfma<<<dim3(NCH, Hh, Gi), blk, 0, stream>>>(qkv, at, paccv,
                                                           paccs);
    merge_agent<<<dim3(Gi * Hh), blk, 0, stream>>>(paccv, paccs, av);
    // 4) fused q attention + dwc + pack -> Opk(=Apk)
    q_attn_dwc<<<dim3((Nn + 63) / 64, Hh, Gi), blk, 0, stream>>>(
        qkv, at, av, dwcw, dwcb, Apk);
    // 5) final projection -> out_g (+bias)
    {
      const int nch = Cc / 128;             // 6
      const int nwg = Mtiles * nch;
      gemm_pk2<<<dim3(nwg), blk, 0, stream>>>(Apk, WPpk, outg, bproj, Mg,
                                              Cc, nch, nwg);
    }
  }
}

// Round 10
// 835.222 us; speedup vs baseline: 3.7095x; 1.0087x over previous
//
#include <hip/hip_runtime.h>

namespace {

constexpr int Bb = 8;
constexpr int Nn = 4097;
constexpr int Cc = 768;
constexpr int Hh = 12;
constexpr int HD = 64;
constexpr int Aa = 49;
constexpr int LDQ = 3 * Cc;        // 2304 (qkv row stride)
constexpr int NCH = 16;            // j-chunks for agent attention
constexpr int CHUNK = (Nn + NCH - 1) / NCH;  // 257
constexpr float SCALE = 0.125f;    // hd^-0.5
constexpr int KP = 1536;           // packed plane row length (hi 768 | lo 768)

typedef short s16x8 __attribute__((ext_vector_type(8)));
typedef short s16x4 __attribute__((ext_vector_type(4)));
typedef float f32x4 __attribute__((ext_vector_type(4)));

struct HL { short h, l; };

// Split fp32 into hi (truncated bf16, exact bits) + lo (RNE bf16 of residual).
__device__ inline HL splitbf(float v) {
  unsigned u = __float_as_uint(v);
  HL r;
  r.h = (short)(u >> 16);
  float hf = __uint_as_float(u & 0xffff0000u);
  float lf = v - hf;
  unsigned ul = __float_as_uint(lf);
  r.l = (short)((ul + 0x7fffu + ((ul >> 16) & 1u)) >> 16);
  return r;
}

__device__ inline unsigned short bf16rne(float v) {
  unsigned u = __float_as_uint(v);
  return (unsigned short)((u + 0x7fffu + ((u >> 16) & 1u)) >> 16);
}
__device__ inline float bf2f(unsigned short s) {
  return __uint_as_float((unsigned)s << 16);
}

// async global->LDS, 16B per lane (linear dest)
__device__ inline void gload16(const short* g, void* l) {
  __builtin_amdgcn_global_load_lds(
      (const __attribute__((address_space(1))) void*)g,
      (__attribute__((address_space(3))) void*)l, 16, 0, 0);
}

// ---------------------------------------------------------------------------
// Pack activations: src[M][768] fp32 -> dst[M][1536] bf16 = [hi | lo], with
// 16B-chunk XOR swizzle within each 64-elem window: chunk' = chunk ^ (m&7).
// ---------------------------------------------------------------------------
__global__ __launch_bounds__(256) void pack_act(
    const float* __restrict__ src, short* __restrict__ dst, int M) {
  int idx = blockIdx.x * 256 + threadIdx.x;
  if (idx >= M * 96) return;
  int m = idx / 96, kc = idx - m * 96;
  const float* s = src + (size_t)m * 768 + kc * 8;
  float4 v0 = *(const float4*)s;
  float4 v1 = *(const float4*)(s + 4);
  s16x8 hv, lv;
  HL r;
  r = splitbf(v0.x); hv[0] = r.h; lv[0] = r.l;
  r = splitbf(v0.y); hv[1] = r.h; lv[1] = r.l;
  r = splitbf(v0.z); hv[2] = r.h; lv[2] = r.l;
  r = splitbf(v0.w); hv[3] = r.h; lv[3] = r.l;
  r = splitbf(v1.x); hv[4] = r.h; lv[4] = r.l;
  r = splitbf(v1.y); hv[5] = r.h; lv[5] = r.l;
  r = splitbf(v1.z); hv[6] = r.h; lv[6] = r.l;
  r = splitbf(v1.w); hv[7] = r.h; lv[7] = r.l;
  int win = (kc >> 3) * 64;
  int jj = ((kc & 7) ^ (m & 7)) * 8;
  short* d = dst + (size_t)m * KP;
  *(s16x8*)&d[win + jj] = hv;
  *(s16x8*)&d[768 + win + jj] = lv;
}

// ---------------------------------------------------------------------------
// Pack weights: W[768][N] fp32 -> Wpk[N][1536] bf16 = [hi | lo], same swizzle
// keyed by (n&7).
// ---------------------------------------------------------------------------
__global__ __launch_bounds__(256) void pack_w(
    const float* __restrict__ W, short* __restrict__ Wpk, int N) {
  int idx = blockIdx.x * 256 + threadIdx.x;
  if (idx >= 96 * N) return;
  int kc = idx / N, n = idx - kc * N;
  s16x8 hv, lv;
#pragma unroll
  for (int i = 0; i < 8; ++i) {
    HL r = splitbf(W[(size_t)(kc * 8 + i) * N + n]);
    hv[i] = r.h; lv[i] = r.l;
  }
  int win = (kc >> 3) * 64;
  int jj = ((kc & 7) ^ (n & 7)) * 8;
  short* d = Wpk + (size_t)n * KP;
  *(s16x8*)&d[win + jj] = hv;
  *(s16x8*)&d[768 + win + jj] = lv;
}

// ---------------------------------------------------------------------------
// C[M x N] = A @ B (+bias) on packed planes. Per 64-K-chunk stage all four
// planes (64KB LDS), 96 mfma per barrier pair, 12 kt iterations.
// 1D grid with bijective XCD swizzle; n-fastest logical order.
// ---------------------------------------------------------------------------
__global__ __launch_bounds__(256) void gemm_pk2(
    const short* __restrict__ Apk, const short* __restrict__ Bpk,
    float* __restrict__ Cm, const float* __restrict__ bias,
    int Mr, int ldc, int nch, int nwg) {
  __shared__ __align__(16) short AsH[128 * 64], AsL[128 * 64];
  __shared__ __align__(16) short BsH[128 * 64], BsL[128 * 64];
  const int t = threadIdx.x;
  const int lane = t & 63;
  const int w = t >> 6;
  const int wr = w >> 1, wc = w & 1;
  const int l15 = lane & 15, l4 = lane >> 4;

  const int j = blockIdx.x;
  const int q = nwg >> 3, r = nwg & 7;
  const int xcd = j & 7, pos = j >> 3;
  const int logical =
      (xcd < r ? xcd * (q + 1) : r * (q + 1) + (xcd - r) * q) + pos;
  const int mt = logical / nch, nc = logical - mt * nch;
  const int m0 = mt * 128, n0 = nc * 128;

  f32x4 acc[4][4];
#pragma unroll
  for (int mi = 0; mi < 4; ++mi)
#pragma unroll
    for (int ni = 0; ni < 4; ++ni) acc[mi][ni] = (f32x4){0.f, 0.f, 0.f, 0.f};

  for (int kt = 0; kt < 12; ++kt) {
    const short* Ab = Apk + (size_t)m0 * KP + kt * 64;
    const short* Bt = Bpk + (size_t)n0 * KP + kt * 64;
    __syncthreads();
#pragma unroll
    for (int i = 0; i < 4; ++i) {
      const int o = (i * 256 + t) * 16;   // byte offset in 16KB plane
      const int row = o >> 7;
      const int ce = (o & 127) >> 1;      // element col (physical)
      gload16(Ab + (size_t)row * KP + ce, (char*)AsH + o);
      gload16(Ab + (size_t)row * KP + 768 + ce, (char*)AsL + o);
      gload16(Bt + (size_t)row * KP + ce, (char*)BsH + o);
      gload16(Bt + (size_t)row * KP + 768 + ce, (char*)BsL + o);
    }
    __syncthreads();
#pragma unroll
    for (int ks = 0; ks < 2; ++ks) {
      s16x8 ah[4], al[4], bh[4], bl[4];
#pragma unroll
      for (int mi = 0; mi < 4; ++mi) {
        int rr = wr * 64 + mi * 16 + l15;
        int off = rr * 64 + ((((ks << 2) + l4) ^ (l15 & 7)) << 3);
        ah[mi] = *(const s16x8*)&AsH[off];
        al[mi] = *(const s16x8*)&AsL[off];
      }
#pragma unroll
      for (int ni = 0; ni < 4; ++ni) {
        int rr = wc * 64 + ni * 16 + l15;
        int off = rr * 64 + ((((ks << 2) + l4) ^ (l15 & 7)) << 3);
        bh[ni] = *(const s16x8*)&BsH[off];
        bl[ni] = *(const s16x8*)&BsL[off];
      }
#pragma unroll
      for (int mi = 0; mi < 4; ++mi)
#pragma unroll
        for (int ni = 0; ni < 4; ++ni) {
          acc[mi][ni] = __builtin_amdgcn_mfma_f32_16x16x32_bf16(
              ah[mi], bh[ni], acc[mi][ni], 0, 0, 0);
          acc[mi][ni] = __builtin_amdgcn_mfma_f32_16x16x32_bf16(
              ah[mi], bl[ni], acc[mi][ni], 0, 0, 0);
          acc[mi][ni] = __builtin_amdgcn_mfma_f32_16x16x32_bf16(
              al[mi], bh[ni], acc[mi][ni], 0, 0, 0);
        }
    }
  }

#pragma unroll
  for (int mi = 0; mi < 4; ++mi) {
#pragma unroll
    for (int jr = 0; jr < 4; ++jr) {
      int gr = m0 + wr * 64 + mi * 16 + l4 * 4 + jr;
      if (gr < Mr) {
#pragma unroll
        for (int ni = 0; ni < 4; ++ni) {
          int gc = n0 + wc * 64 + ni * 16 + l15;
          float v = acc[mi][ni][jr];
          if (bias) v += bias[gc];
          Cm[(size_t)gr * ldc + gc] = v;
        }
      }
    }
  }
}

// ---------------------------------------------------------------------------
// Adaptive-pool agents: at[bg,a,c] = mean over q rows [s,e) of q[bg,l,c].
// 192 threads, float4 over c.
// ---------------------------------------------------------------------------
__global__ __launch_bounds__(192) void pool_agents(
    const float* __restrict__ qkv, float* __restrict__ at) {
  const int ba = blockIdx.x;
  const int bg = ba / Aa, a = ba % Aa;
  const int s = (a * 4096) / 49;
  const int e = ((a + 1) * 4096 + 48) / 49;
  const float w = 1.0f / (float)(e - s);
  const int c4 = threadIdx.x * 4;
  f32x4 sum = (f32x4){0.f, 0.f, 0.f, 0.f};
#pragma unroll 4
  for (int l = s; l < e; ++l) {
    const float4 v = *(const float4*)&qkv[(size_t)(bg * Nn + l) * LDQ + c4];
    sum[0] += v.x; sum[1] += v.y; sum[2] += v.z; sum[3] += v.w;
  }
  float4 o;
  o.x = sum[0] * w; o.y = sum[1] * w; o.z = sum[2] * w; o.w = sum[3] * w;
  *(float4*)&at[(size_t)(bg * Aa + a) * Cc + c4] = o;
}

// ---------------------------------------------------------------------------
// Agent attention via MFMA split-bf16. Per (chunk,h,bg): 64(agents,pad) rows.
// Tiles of 64 j: S = ah @ K^T (MFMA), P = exp(S*scale) (masked), O += P @ V.
// P planes ALIAS the K planes -> 48KB LDS. NCH=16 chunks -> 1536 blocks.
// ---------------------------------------------------------------------------
__global__ __launch_bounds__(256) void agent_attn_mfma(
    const float* __restrict__ qkv, const float* __restrict__ at,
    float* __restrict__ paccv, float* __restrict__ paccs) {
  const int chunk = blockIdx.x, h = blockIdx.y, bg = blockIdx.z;
  __shared__ __align__(16) short AhH[4096], AhL[4096];  // ah [a][d]
  __shared__ __align__(16) short KH[4096], KL[4096];    // K [j][d]; P aliases
  __shared__ __align__(16) short VtH[4096], VtL[4096];  // V^T [c][j]
  const int t = threadIdx.x;
  const int w = t >> 6, lane = t & 63, l15 = lane & 15, l4 = lane >> 4;

  // stage ah (rows >=49 zero), chunk-XOR (a&7)
  for (int idx = t; idx < 512; idx += 256) {
    int a = idx >> 3, c8 = idx & 7;
    float vals[8];
    if (a < Aa) {
      const float* src = &at[(size_t)(bg * Aa + a) * Cc + h * HD + c8 * 8];
      *(float4*)&vals[0] = *(const float4*)src;
      *(float4*)&vals[4] = *(const float4*)(src + 4);
    } else {
#pragma unroll
      for (int i = 0; i < 8; ++i) vals[i] = 0.f;
    }
    s16x8 hv, lv;
#pragma unroll
    for (int i = 0; i < 8; ++i) {
      HL r = splitbf(vals[i]);
      hv[i] = r.h; lv[i] = r.l;
    }
    int pos = a * 64 + ((c8 ^ (a & 7)) << 3);
    *(s16x8*)&AhH[pos] = hv;
    *(s16x8*)&AhL[pos] = lv;
  }

  f32x4 acc[4];
#pragma unroll
  for (int ni = 0; ni < 4; ++ni) acc[ni] = (f32x4){0.f, 0.f, 0.f, 0.f};
  float rs[4] = {0.f, 0.f, 0.f, 0.f};

  const int jstart = chunk * CHUNK;
  const int jend = min(jstart + CHUNK, Nn);
  const int srow = t >> 2, sc0 = (t & 3) * 16;  // staging coords

  for (int j0 = jstart; j0 < jend; j0 += 64) {
    __syncthreads();  // prev PV done (P reads from K planes finished)
    // ---- stage K (vectorized) and V^T (scalar transpose) ----
    {
      int jg = j0 + srow;
      float kv[16], vv[16];
      if (jg < jend) {
        const float* p = &qkv[(size_t)(bg * Nn + jg) * LDQ + Cc + h * HD + sc0];
#pragma unroll
        for (int r = 0; r < 4; ++r) {
          *(float4*)&kv[r * 4] = *(const float4*)(p + r * 4);
          *(float4*)&vv[r * 4] = *(const float4*)(p + Cc + r * 4);
        }
      } else {
#pragma unroll
        for (int i = 0; i < 16; ++i) { kv[i] = 0.f; vv[i] = 0.f; }
      }
#pragma unroll
      for (int r = 0; r < 2; ++r) {
        s16x8 hv, lv;
#pragma unroll
        for (int i = 0; i < 8; ++i) {
          HL s = splitbf(kv[r * 8 + i]);
          hv[i] = s.h; lv[i] = s.l;
        }
        int ch = (sc0 >> 3) + r;
        int pos = srow * 64 + ((ch ^ (srow & 7)) << 3);
        *(s16x8*)&KH[pos] = hv;
        *(s16x8*)&KL[pos] = lv;
      }
#pragma unroll
      for (int i = 0; i < 16; ++i) {
        HL s = splitbf(vv[i]);
        int c = sc0 + i;
        int pos = c * 64 + ((((srow >> 3) ^ (c & 7)) << 3)) + (srow & 7);
        VtH[pos] = s.h;
        VtL[pos] = s.l;
      }
    }
    __syncthreads();

    // ---- S = ah @ K^T ----
    f32x4 s[4];
#pragma unroll
    for (int ni = 0; ni < 4; ++ni) s[ni] = (f32x4){0.f, 0.f, 0.f, 0.f};
#pragma unroll
    for (int ks = 0; ks < 2; ++ks) {
      int sw = (((ks << 2) + l4) ^ (l15 & 7)) << 3;
      s16x8 ahh = *(const s16x8*)&AhH[(w * 16 + l15) * 64 + sw];
      s16x8 ahl = *(const s16x8*)&AhL[(w * 16 + l15) * 64 + sw];
#pragma unroll
      for (int ni = 0; ni < 4; ++ni) {
        s16x8 kh = *(const s16x8*)&KH[(ni * 16 + l15) * 64 + sw];
        s16x8 kl = *(const s16x8*)&KL[(ni * 16 + l15) * 64 + sw];
        s[ni] = __builtin_amdgcn_mfma_f32_16x16x32_bf16(ahh, kh, s[ni], 0, 0, 0);
        s[ni] = __builtin_amdgcn_mfma_f32_16x16x32_bf16(ahh, kl, s[ni], 0, 0, 0);
        s[ni] = __builtin_amdgcn_mfma_f32_16x16x32_bf16(ahl, kh, s[ni], 0, 0, 0);
      }
    }
    __syncthreads();  // all waves done reading K -> P may overwrite

    // ---- P = exp (masked), row-sum accumulate, transpose-write into K planes
#pragma unroll
    for (int ni = 0; ni < 4; ++ni) {
#pragma unroll
      for (int reg = 0; reg < 4; ++reg) {
        int jj = l15 + 16 * ni;
        float pv = (j0 + jj < jend) ? expf(s[ni][reg] * SCALE) : 0.f;
        rs[reg] += pv;
        HL r = splitbf(pv);
        int a = w * 16 + l4 * 4 + reg;
        int pos = a * 64 + ((((jj >> 3) ^ (a & 7)) << 3)) + (jj & 7);
        KH[pos] = r.h;
        KL[pos] = r.l;
      }
    }
    __syncthreads();

    // ---- O += P @ V ----
#pragma unroll
    for (int ks = 0; ks < 2; ++ks) {
      int sw = (((ks << 2) + l4) ^ (l15 & 7)) << 3;
      s16x8 ph = *(const s16x8*)&KH[(w * 16 + l15) * 64 + sw];
      s16x8 pl = *(const s16x8*)&KL[(w * 16 + l15) * 64 + sw];
#pragma unroll
      for (int ni = 0; ni < 4; ++ni) {
        s16x8 vh = *(const s16x8*)&VtH[(ni * 16 + l15) * 64 + sw];
        s16x8 vl = *(const s16x8*)&VtL[(ni * 16 + l15) * 64 + sw];
        acc[ni] = __builtin_amdgcn_mfma_f32_16x16x32_bf16(ph, vh, acc[ni], 0, 0, 0);
        acc[ni] = __builtin_amdgcn_mfma_f32_16x16x32_bf16(ph, vl, acc[ni], 0, 0, 0);
        acc[ni] = __builtin_amdgcn_mfma_f32_16x16x32_bf16(pl, vh, acc[ni], 0, 0, 0);
      }
    }
  }

  // ---- epilogue: reduce row-sums across the 16 j-lanes, write partials ----
#pragma unroll
  for (int reg = 0; reg < 4; ++reg) {
    rs[reg] += __shfl_xor(rs[reg], 1);
    rs[reg] += __shfl_xor(rs[reg], 2);
    rs[reg] += __shfl_xor(rs[reg], 4);
    rs[reg] += __shfl_xor(rs[reg], 8);
  }
  const int basev = ((bg * Hh + h) * NCH + chunk) * (Aa * 64);
#pragma unroll
  for (int reg = 0; reg < 4; ++reg) {
    int a = w * 16 + l4 * 4 + reg;
    if (a < Aa) {
#pragma unroll
      for (int ni = 0; ni < 4; ++ni)
        paccv[basev + a * 64 + l15 + 16 * ni] = acc[ni][reg];
      if (l15 == 0)
        paccs[((bg * Hh + h) * NCH + chunk) * Aa + a] = rs[reg];
    }
  }
}

// ---------------------------------------------------------------------------
// Merge chunk partials -> agent_v[bgh,a,c]
// ---------------------------------------------------------------------------
__global__ __launch_bounds__(256) void merge_agent(
    const float* __restrict__ paccv, const float* __restrict__ paccs,
    float* __restrict__ av) {
  const int bh = blockIdx.x;
  const int t = threadIdx.x;
  for (int idx = t; idx < Aa * HD; idx += 256) {
    int a = idx >> 6;
    float vs = 0.f, ss = 0.f;
#pragma unroll
    for (int ch = 0; ch < NCH; ++ch) {
      vs += paccv[(size_t)((bh * NCH + ch)) * (Aa * 64) + idx];
      ss += paccs[(bh * NCH + ch) * Aa + a];
    }
    av[(size_t)bh * (Aa * HD) + idx] = vs / ss;
  }
}

// ---------------------------------------------------------------------------
// FUSED q attention + depthwise conv + split-pack. Per (qtile,h,bg): 64 q
// rows x this head's 64 channels. After PV, the v tile (rows i0-1..i0+64,
// bf16) is staged into the dead Q/P LDS region; dwc reads come from LDS.
// 48KB LDS total; outp never materialized.
// ---------------------------------------------------------------------------
__global__ __launch_bounds__(256) void q_attn_dwc(
    const float* __restrict__ qkv, const float* __restrict__ at,
    const float* __restrict__ av, const float* __restrict__ dwcw,
    const float* __restrict__ dwcb, short* __restrict__ Opk) {
  const int i0 = blockIdx.x * 64, h = blockIdx.y, bg = blockIdx.z;
  __shared__ __align__(16) short SMEM[24576];   // 48KB, manually partitioned
  short* AhH = SMEM;             // [a][d] 8KB
  short* AhL = SMEM + 4096;
  short* AvH = SMEM + 8192;      // av^T [c][a]
  short* AvL = SMEM + 12288;
  short* QH  = SMEM + 16384;     // q [row][d]; P alias; then v-stage alias
  short* QL  = SMEM + 20480;
  const int t = threadIdx.x;
  const int w = t >> 6, lane = t & 63, l15 = lane & 15, l4 = lane >> 4;

  // stage ah + av^T (rows/cols >=49 zero)
  for (int idx = t; idx < 512; idx += 256) {
    int a = idx >> 3, c8 = idx & 7;
    float vah[8], vav[8];
    if (a < Aa) {
      const float* s1 = &at[(size_t)(bg * Aa + a) * Cc + h * HD + c8 * 8];
      const float* s2 = &av[(size_t)(bg * Hh + h) * (Aa * HD) + a * HD + c8 * 8];
      *(float4*)&vah[0] = *(const float4*)s1;
      *(float4*)&vah[4] = *(const float4*)(s1 + 4);
      *(float4*)&vav[0] = *(const float4*)s2;
      *(float4*)&vav[4] = *(const float4*)(s2 + 4);
    } else {
#pragma unroll
      for (int i = 0; i < 8; ++i) { vah[i] = 0.f; vav[i] = 0.f; }
    }
    s16x8 hv, lv;
#pragma unroll
    for (int i = 0; i < 8; ++i) {
      HL r = splitbf(vah[i]);
      hv[i] = r.h; lv[i] = r.l;
    }
    int pos = a * 64 + ((c8 ^ (a & 7)) << 3);
    *(s16x8*)&AhH[pos] = hv;
    *(s16x8*)&AhL[pos] = lv;
#pragma unroll
    for (int i = 0; i < 8; ++i) {
      HL r = splitbf(vav[i]);
      int c = c8 * 8 + i;
      int pos2 = c * 64 + ((((a >> 3) ^ (c & 7)) << 3)) + (a & 7);
      AvH[pos2] = r.h;
      AvL[pos2] = r.l;
    }
  }
  // stage q tile (rows beyond Nn zero)
  {
    int row = t >> 2, c0 = (t & 3) * 16;
    int ig = i0 + row;
    float qv[16];
    if (ig < Nn) {
      const float* p = &qkv[(size_t)(bg * Nn + ig) * LDQ + h * HD + c0];
#pragma unroll
      for (int r = 0; r < 4; ++r) *(float4*)&qv[r * 4] = *(const float4*)(p + r * 4);
    } else {
#pragma unroll
      for (int i = 0; i < 16; ++i) qv[i] = 0.f;
    }
#pragma unroll
    for (int r = 0; r < 2; ++r) {
      s16x8 hv, lv;
#pragma unroll
      for (int i = 0; i < 8; ++i) {
        HL s = splitbf(qv[r * 8 + i]);
        hv[i] = s.h; lv[i] = s.l;
      }
      int ch = (c0 >> 3) + r;
      int pos = row * 64 + ((ch ^ (row & 7)) << 3);
      *(s16x8*)&QH[pos] = hv;
      *(s16x8*)&QL[pos] = lv;
    }
  }
  __syncthreads();

  // ---- S = q @ ah^T ----
  f32x4 s[4];
#pragma unroll
  for (int ni = 0; ni < 4; ++ni) s[ni] = (f32x4){0.f, 0.f, 0.f, 0.f};
#pragma unroll
  for (int ks = 0; ks < 2; ++ks) {
    int sw = (((ks << 2) + l4) ^ (l15 & 7)) << 3;
    s16x8 qh = *(const s16x8*)&QH[(w * 16 + l15) * 64 + sw];
    s16x8 ql = *(const s16x8*)&QL[(w * 16 + l15) * 64 + sw];
#pragma unroll
    for (int ni = 0; ni < 4; ++ni) {
      s16x8 bh = *(const s16x8*)&AhH[(ni * 16 + l15) * 64 + sw];
      s16x8 bl = *(const s16x8*)&AhL[(ni * 16 + l15) * 64 + sw];
      s[ni] = __builtin_amdgcn_mfma_f32_16x16x32_bf16(qh, bh, s[ni], 0, 0, 0);
      s[ni] = __builtin_amdgcn_mfma_f32_16x16x32_bf16(qh, bl, s[ni], 0, 0, 0);
      s[ni] = __builtin_amdgcn_mfma_f32_16x16x32_bf16(ql, bh, s[ni], 0, 0, 0);
    }
  }
  __syncthreads();  // all waves done reading Q -> P may overwrite

  // ---- softmax over agents (within-wave) + transpose-write P into Q planes
  float rsum[4] = {0.f, 0.f, 0.f, 0.f};
#pragma unroll
  for (int ni = 0; ni < 4; ++ni) {
#pragma unroll
    for (int reg = 0; reg < 4; ++reg) {
      int a = l15 + 16 * ni;
      float pv = (a < Aa) ? expf(s[ni][reg] * SCALE) : 0.f;
      s[ni][reg] = pv;
      rsum[reg] += pv;
    }
  }
#pragma unroll
  for (int reg = 0; reg < 4; ++reg) {
    rsum[reg] += __shfl_xor(rsum[reg], 1);
    rsum[reg] += __shfl_xor(rsum[reg], 2);
    rsum[reg] += __shfl_xor(rsum[reg], 4);
    rsum[reg] += __shfl_xor(rsum[reg], 8);
    rsum[reg] = 1.0f / rsum[reg];
  }
#pragma unroll
  for (int ni = 0; ni < 4; ++ni) {
#pragma unroll
    for (int reg = 0; reg < 4; ++reg) {
      HL r = splitbf(s[ni][reg] * rsum[reg]);
      int row = w * 16 + l4 * 4 + reg;
      int a = l15 + 16 * ni;
      int pos = row * 64 + ((((a >> 3) ^ (row & 7)) << 3)) + (a & 7);
      QH[pos] = r.h;
      QL[pos] = r.l;
    }
  }
  __syncthreads();

  // ---- O = P @ agent_v ----
  f32x4 o[4];
#pragma unroll
  for (int ni = 0; ni < 4; ++ni) o[ni] = (f32x4){0.f, 0.f, 0.f, 0.f};
#pragma unroll
  for (int ks = 0; ks < 2; ++ks) {
    int sw = (((ks << 2) + l4) ^ (l15 & 7)) << 3;
    s16x8 ph = *(const s16x8*)&QH[(w * 16 + l15) * 64 + sw];
    s16x8 pl = *(const s16x8*)&QL[(w * 16 + l15) * 64 + sw];
#pragma unroll
    for (int ni = 0; ni < 4; ++ni) {
      s16x8 vh = *(const s16x8*)&AvH[(ni * 16 + l15) * 64 + sw];
      s16x8 vl = *(const s16x8*)&AvL[(ni * 16 + l15) * 64 + sw];
      o[ni] = __builtin_amdgcn_mfma_f32_16x16x32_bf16(ph, vh, o[ni], 0, 0, 0);
      o[ni] = __builtin_amdgcn_mfma_f32_16x16x32_bf16(ph, vl, o[ni], 0, 0, 0);
      o[ni] = __builtin_amdgcn_mfma_f32_16x16x32_bf16(pl, vh, o[ni], 0, 0, 0);
    }
  }
  __syncthreads();  // all waves done reading P -> v-stage may overwrite

  // ---- stage v tile (bf16 RNE): rows i0-1 .. i0+64, this head's 64 ch ----
  constexpr int VLD = 72;                       // row stride in shorts
  unsigned short* vlds = (unsigned short*)QH;   // 66*72*2 = 9504B < 16KB
  for (int idx = t; idx < 66 * 16; idx += 256) {
    int row = idx >> 4, cs = (idx & 15) << 2;
    int gr = i0 - 1 + row;
    float4 v = make_float4(0.f, 0.f, 0.f, 0.f);
    if (gr >= 0 && gr < 4096)
      v = *(const float4*)&qkv[((size_t)bg * Nn + gr) * LDQ + 2 * Cc + h * HD + cs];
    unsigned short* d = &vlds[row * VLD + cs];
    d[0] = bf16rne(v.x); d[1] = bf16rne(v.y);
    d[2] = bf16rne(v.z); d[3] = bf16rne(v.w);
  }
  __syncthreads();

  // ---- epilogue: + dwc(v) from LDS, split, pack straight into Opk ----
#pragma unroll
  for (int reg = 0; reg < 4; ++reg) {
    int ig = i0 + w * 16 + l4 * 4 + reg;
    if (ig < Nn) {
      const size_t m = (size_t)bg * Nn + ig;
      const int rl = ig - i0 + 1;               // local row in vlds
#pragma unroll
      for (int ni = 0; ni < 4; ++ni) {
        int cl = l15 + 16 * ni;
        int c = h * HD + cl;                    // global channel
        float val = o[ni][reg];
        if (ig < Nn - 1) {
          float vm = bf2f(vlds[(rl - 1) * VLD + cl]);
          float v0 = bf2f(vlds[rl * VLD + cl]);
          float vp = bf2f(vlds[(rl + 1) * VLD + cl]);
          val += dwcw[c * 3] * vm + dwcw[c * 3 + 1] * v0 +
                 dwcw[c * 3 + 2] * vp + dwcb[c];
        }
        HL r = splitbf(val);
        int kc = c >> 3;
        int win = (kc >> 3) * 64;               // = h*64
        int jj = ((kc & 7) ^ ((int)m & 7)) * 8 + (c & 7);
        Opk[m * KP + win + jj] = r.h;
        Opk[m * KP + 768 + win + jj] = r.l;
      }
    }
  }
}

}  // namespace

extern "C" void kernel_launch(void* const* d_in, const int* in_sizes, int n_in,
                              void* d_out, int out_size, void* d_ws,
                              size_t ws_size, hipStream_t stream) {
  const float* x = (const float*)d_in[0];
  const float* Wqkv = (const float*)d_in[1];
  const float* Wproj = (const float*)d_in[2];
  const float* bproj = (const float*)d_in[3];
  const float* dwcw = (const float*)d_in[4];
  const float* dwcb = (const float*)d_in[5];
  float* out = (float*)d_out;

  // --- fixed workspace: packed weight planes ---
  char* p = (char*)d_ws;
  short* WQpk = (short*)p; p += (size_t)LDQ * KP * 2;   // 7,077,888 B
  short* WPpk = (short*)p; p += (size_t)Cc * KP * 2;    // 2,359,296 B
  const size_t fixedBytes = (size_t)p - (size_t)d_ws;

  // --- choose group size G (largest that fits) ---
  auto bytesFor = [&](int G) -> size_t {
    size_t Mg = (size_t)G * Nn;
    size_t Mpad = ((Mg + 127) / 128) * 128;
    size_t fl = Mg * LDQ +
                (size_t)G * (Aa * Cc + Hh * NCH * Aa * 64 + Hh * NCH * Aa +
                             Hh * Aa * HD);
    return fixedBytes + fl * 4 + Mpad * KP * 2;            // + Apk/Opk
  };
  int G = 1;
  for (int g = Bb; g >= 1; --g) {
    if (bytesFor(g) <= ws_size) { G = g; break; }
  }

  const size_t MgMax = (size_t)G * Nn;
  float* qkv = (float*)p;
  float* at = qkv + MgMax * LDQ;
  float* paccv = at + (size_t)G * Aa * Cc;
  float* paccs = paccv + (size_t)G * Hh * NCH * Aa * 64;
  float* av = paccs + (size_t)G * Hh * NCH * Aa;
  short* Apk = (short*)(av + (size_t)G * Hh * Aa * HD);   // aliased as Opk

  dim3 blk(256);
  // 0) pack weights (once per launch; deterministic)
  pack_w<<<dim3((96 * LDQ + 255) / 256), blk, 0, stream>>>(Wqkv, WQpk, LDQ);
  pack_w<<<dim3((96 * Cc + 255) / 256), blk, 0, stream>>>(Wproj, WPpk, Cc);

  for (int b0 = 0; b0 < Bb; b0 += G) {
    const int Gi = (b0 + G <= Bb) ? G : (Bb - b0);
    const int Mg = Gi * Nn;
    const int Mtiles = (Mg + 127) / 128;
    const float* xg = x + (size_t)b0 * Nn * Cc;
    float* outg = out + (size_t)b0 * Nn * Cc;

    // 1) pack x -> Apk, then qkv = x @ Wqkv (packed MFMA GEMM)
    pack_act<<<dim3((Mg * 96 + 255) / 256), blk, 0, stream>>>(xg, Apk, Mg);
    {
      const int nch = LDQ / 128;            // 18
      const int nwg = Mtiles * nch;
      gemm_pk2<<<dim3(nwg), blk, 0, stream>>>(Apk, WQpk, qkv, nullptr, Mg,
                                              LDQ, nch, nwg);
    }
    // 2) agent tokens (adaptive pool of q)
    pool_agents<<<dim3(Gi * Aa), dim3(192), 0, stream>>>(qkv, at);
    // 3) agent attention partials (MFMA) + merge -> agent_v
    agent_attn_mfma<<<dim3(NCH, Hh, Gi), blk, 0, stream>>>(qkv, at, paccv,
                                                           paccs);
    merge_agent<<<dim3(Gi * Hh), blk, 0, stream>>>(paccv, paccs, av);
    // 4) fused q attention + dwc + pack -> Opk(=Apk)
    q_attn_dwc<<<dim3((Nn + 63) / 64, Hh, Gi), blk, 0, stream>>>(
        qkv, at, av, dwcw, dwcb, Apk);
    // 5) final projection -> out_g (+bias)
    {
      const int nch = Cc / 128;             // 6
      const int nwg = Mtiles * nch;
      gemm_pk2<<<dim3(nwg), blk, 0, stream>>>(Apk, WPpk, outg, bproj, Mg,
                                              Cc, nch, nwg);
    }
  }
}